// Round 11
// baseline (32375.613 us; speedup 1.0000x reference)
//
#include <hip/hip_runtime.h>
#include <math.h>

typedef float f4 __attribute__((ext_vector_type(4)));
typedef _Float16 h4 __attribute__((ext_vector_type(4)));
typedef _Float16 h8 __attribute__((ext_vector_type(8)));

// ---------------- workspace layout (float offsets), total 32,210,944 = 128.84 MB (R10-proven) ----
// AX  : A@x all t [i][t*128+b*2+c]      6,144,000
// AHC : A@[H] fp32 [1024][8192], col = b*128 + l*64 + k   8,388,608  (Xr alias)
// C0,C1: cell state fp32 [b][1000][64]  2 x 4,096,000   (At alias in C0)
// HTh/l: H^T split f16 [8192][1024], row n = b*128 + l*64 + h   2 x 4,194,304
// Ah/Al: split f16 A [1024][1024]       2 x 524,288
// W0T [64][256], W1T [128][256] fp32
#define WS_AX    0
#define WS_AHC   6144000
#define WS_C0    14532608
#define WS_C1    18628608
#define WS_HTH   22724608
#define WS_HTL   26918912
#define WS_A16H  31113216
#define WS_A16L  31637504
#define WS_W0T   32161792
#define WS_W1T   32178176
// end = 32,210,944

// ---------------- A = softmax(relu(E1 @ E2^T)) in fp64, store A^T ----------------
__global__ __launch_bounds__(256) void compute_A(const float* __restrict__ E1,
                                                 const float* __restrict__ E2,
                                                 float* __restrict__ At)
{
    __shared__ double z[1000];
    __shared__ double red[256];
    __shared__ double e1[16];
    const int i = blockIdx.x;
    const int tid = threadIdx.x;
    if (tid < 16) e1[tid] = (double)E1[i * 16 + tid];
    __syncthreads();
    double lmax = -1e300;
    for (int j = tid; j < 1000; j += 256) {
        double s = 0.0;
        #pragma unroll
        for (int c = 0; c < 16; ++c) s += e1[c] * (double)E2[j * 16 + c];
        if (s < 0.0) s = 0.0;
        z[j] = s;
        if (s > lmax) lmax = s;
    }
    red[tid] = lmax; __syncthreads();
    for (int off = 128; off > 0; off >>= 1) {
        if (tid < off) red[tid] = fmax(red[tid], red[tid + off]);
        __syncthreads();
    }
    const double zmax = red[0];
    __syncthreads();
    double lsum = 0.0;
    for (int j = tid; j < 1000; j += 256) {
        double e = exp(z[j] - zmax);
        z[j] = e;
        lsum += e;
    }
    red[tid] = lsum; __syncthreads();
    for (int off = 128; off > 0; off >>= 1) {
        if (tid < off) red[tid] += red[tid + off];
        __syncthreads();
    }
    const double inv = 1.0 / red[0];
    for (int j = tid; j < 1000; j += 256)
        At[(size_t)j * 1000 + i] = (float)(z[j] * inv);
}

// ---------------- x [B,T,N,C] -> Xr [j][t*128 + b*2 + c] ----------------
__global__ __launch_bounds__(256) void transpose_x(const float* __restrict__ x,
                                                   float* __restrict__ Xr)
{
    int o = blockIdx.x * 256 + threadIdx.x;
    if (o >= 6144000) return;
    int j = o / 6144;
    int r = o - j * 6144;
    int t = r >> 7;
    int q = r & 127;
    int b = q >> 1;
    int c = q & 1;
    Xr[o] = x[(((size_t)(b * 48 + t)) * 1000 + j) * 2 + c];
}

__global__ __launch_bounds__(256) void zero_kernel(float* __restrict__ p, int n4)
{
    int i = blockIdx.x * 256 + threadIdx.x;
    if (i < n4) { f4 z = {0.f, 0.f, 0.f, 0.f}; ((f4*)p)[i] = z; }
}

// ---------------- weight transposes to [k][256] fp32 (once; R7-proven) ----------------
__global__ __launch_bounds__(256) void prep_w(const float* __restrict__ Wh0,
                                              const float* __restrict__ Wx1,
                                              const float* __restrict__ Wh1,
                                              float* __restrict__ W0T,
                                              float* __restrict__ W1T)
{
    int idx = blockIdx.x * 256 + threadIdx.x;
    if (idx < 16384) {
        int k = idx >> 8, o = idx & 255;
        W0T[idx] = Wh0[o * 64 + k];
    }
    int j = idx - 16384;
    if (j >= 0 && j < 32768) {
        int k = j >> 8, o = j & 255;
        W1T[j] = (k < 64) ? Wx1[o * 64 + k] : Wh1[o * 64 + (k - 64)];
    }
}

// ---------------- split A^T fp32 -> Ah/Al f16 [m=1024][k=1024] ----------------
__global__ __launch_bounds__(256) void prep_A(const float* __restrict__ At,
                                              _Float16* __restrict__ Ahh,
                                              _Float16* __restrict__ All)
{
    int idx = blockIdx.x * 256 + threadIdx.x;   // 1,048,576
    int m = idx >> 10, k = idx & 1023;
    float v = (m < 1000 && k < 1000) ? At[(size_t)k * 1000 + m] : 0.f;
    _Float16 hi = (_Float16)v;
    Ahh[idx] = hi;
    All[idx] = (_Float16)((v - (float)hi) * 2048.f);
}

// ---------------- fp32 GEMM (used once for AX; R1-proven) ----------------
__global__ __launch_bounds__(256) void gemm1000(const float* __restrict__ At,
                                                const float* __restrict__ B,
                                                float* __restrict__ C,
                                                int ncols)
{
    __shared__ float As[8][64];
    __shared__ float Bs[8][128];
    const int tid = threadIdx.x;
    const int tx = tid & 15;
    const int ty = tid >> 4;
    const int row0 = blockIdx.x * 64;
    const int col0 = blockIdx.y * 128;
    const int lm = tid & 63;
    const int lk = tid >> 6;
    const int bcol = tid & 127;
    const int bk = tid >> 7;
    const bool arow_ok = (row0 + lm) < 1000;

    float acc[4][8];
    #pragma unroll
    for (int r = 0; r < 4; ++r)
        #pragma unroll
        for (int c = 0; c < 8; ++c) acc[r][c] = 0.f;

    for (int k0 = 0; k0 < 1000; k0 += 8) {
        float a0 = arow_ok ? At[(size_t)(k0 + lk) * 1000 + row0 + lm] : 0.f;
        float a1 = arow_ok ? At[(size_t)(k0 + lk + 4) * 1000 + row0 + lm] : 0.f;
        float bv[4];
        #pragma unroll
        for (int kk = 0; kk < 4; ++kk)
            bv[kk] = B[(size_t)(k0 + bk * 4 + kk) * ncols + col0 + bcol];
        __syncthreads();
        As[lk][lm] = a0;
        As[lk + 4][lm] = a1;
        #pragma unroll
        for (int kk = 0; kk < 4; ++kk) Bs[bk * 4 + kk][bcol] = bv[kk];
        __syncthreads();
        #pragma unroll
        for (int k = 0; k < 8; ++k) {
            f4 av = *(const f4*)&As[k][ty * 4];
            f4 b0 = *(const f4*)&Bs[k][tx * 8];
            f4 b1 = *(const f4*)&Bs[k][tx * 8 + 4];
            #pragma unroll
            for (int r = 0; r < 4; ++r) {
                float a = av[r];
                acc[r][0] = fmaf(a, b0[0], acc[r][0]);
                acc[r][1] = fmaf(a, b0[1], acc[r][1]);
                acc[r][2] = fmaf(a, b0[2], acc[r][2]);
                acc[r][3] = fmaf(a, b0[3], acc[r][3]);
                acc[r][4] = fmaf(a, b1[0], acc[r][4]);
                acc[r][5] = fmaf(a, b1[1], acc[r][5]);
                acc[r][6] = fmaf(a, b1[2], acc[r][6]);
                acc[r][7] = fmaf(a, b1[3], acc[r][7]);
            }
        }
    }
    #pragma unroll
    for (int r = 0; r < 4; ++r) {
        int row = row0 + ty * 4 + r;
        if (row < 1000) {
            f4 o0 = {acc[r][0], acc[r][1], acc[r][2], acc[r][3]};
            f4 o1 = {acc[r][4], acc[r][5], acc[r][6], acc[r][7]};
            *(f4*)&C[(size_t)row * ncols + col0 + tx * 8]     = o0;
            *(f4*)&C[(size_t)row * ncols + col0 + tx * 8 + 4] = o1;
        }
    }
}

// ---------------- merged MFMA GEMM (R7 body): AHC[1024][8192] = A @ HT^T ----------------
// BM=64 BN=128 BK=32; XCD-aware: xcd=bid&7 owns n-panels xcd*8..+8 (4MB, L2-resident).
#define GL16(srcp, dstoff) \
    __builtin_amdgcn_global_load_lds((const __attribute__((address_space(1))) unsigned int*)(srcp), \
        (__attribute__((address_space(3))) unsigned int*)(lds + (dstoff)), 16, 0, 0)

__device__ __forceinline__ int swzb(int row, int lg) {
    return row * 64 + ((lg ^ ((row ^ (row >> 2)) & 3)) << 4);
}

__global__ __launch_bounds__(256, 2) void gemm_m(
    const _Float16* __restrict__ Ahg, const _Float16* __restrict__ Alg,
    const _Float16* __restrict__ Bhg, const _Float16* __restrict__ Blg,
    float* __restrict__ Cout)
{
    __shared__ __align__(1024) char lds[24576];
    const int tid = threadIdx.x;
    const int lane = tid & 63;
    const int w = tid >> 6;
    const int lg = lane >> 4, l15 = lane & 15;
    const int xcd = blockIdx.x & 7;
    const int j = blockIdx.x >> 3;
    const int m0 = (j >> 3) * 64;
    const int n0 = (xcd * 8 + (j & 7)) * 128;

    const int r16 = lane >> 2;
    const int sd = lane & 3;
    const char* src[6];
    #pragma unroll
    for (int q = 0; q < 6; ++q) {
        const int c = w * 6 + q;
        int row;
        const _Float16* g;
        if (c < 4)       { row = (c)      * 16 + r16; g = Ahg + (size_t)(m0 + row) * 1024; }
        else if (c < 8)  { row = (c - 4)  * 16 + r16; g = Alg + (size_t)(m0 + row) * 1024; }
        else if (c < 16) { row = (c - 8)  * 16 + r16; g = Bhg + (size_t)(n0 + row) * 1024; }
        else             { row = (c - 16) * 16 + r16; g = Blg + (size_t)(n0 + row) * 1024; }
        const int cg = sd ^ ((row ^ (row >> 2)) & 3);
        src[q] = (const char*)(g + cg * 8);
    }

    f4 acc0[4][2], acc1[4][2];
    #pragma unroll
    for (int a = 0; a < 4; ++a)
        #pragma unroll
        for (int b = 0; b < 2; ++b) {
            acc0[a][b] = (f4){0.f, 0.f, 0.f, 0.f};
            acc1[a][b] = (f4){0.f, 0.f, 0.f, 0.f};
        }

    for (int ks = 0; ks < 32; ++ks) {
        const int kadv = ks * 64;
        #pragma unroll
        for (int q = 0; q < 6; ++q)
            GL16(src[q] + kadv, (w * 6 + q) * 1024);
        __syncthreads();

        h8 fa[4], fl[4], bh[2], bl[2];
        #pragma unroll
        for (int mf = 0; mf < 4; ++mf) {
            const int ob = swzb(mf * 16 + l15, lg);
            fa[mf] = *(const h8*)(lds + ob);
            fl[mf] = *(const h8*)(lds + 4096 + ob);
        }
        #pragma unroll
        for (int nf = 0; nf < 2; ++nf) {
            const int ob = swzb(w * 32 + nf * 16 + l15, lg);
            bh[nf] = *(const h8*)(lds + 8192 + ob);
            bl[nf] = *(const h8*)(lds + 16384 + ob);
        }
        __syncthreads();

        #pragma unroll
        for (int nf = 0; nf < 2; ++nf)
            #pragma unroll
            for (int mf = 0; mf < 4; ++mf) {
                acc0[mf][nf] = __builtin_amdgcn_mfma_f32_16x16x32_f16(fa[mf], bh[nf], acc0[mf][nf], 0, 0, 0);
                acc1[mf][nf] = __builtin_amdgcn_mfma_f32_16x16x32_f16(fa[mf], bl[nf], acc1[mf][nf], 0, 0, 0);
                acc1[mf][nf] = __builtin_amdgcn_mfma_f32_16x16x32_f16(fl[mf], bh[nf], acc1[mf][nf], 0, 0, 0);
            }
    }

    #pragma unroll
    for (int mf = 0; mf < 4; ++mf)
        #pragma unroll
        for (int nf = 0; nf < 2; ++nf) {
            const int row = m0 + mf * 16 + lg * 4;
            const int col = n0 + w * 32 + nf * 16 + l15;
            #pragma unroll
            for (int e = 0; e < 4; ++e)
                Cout[(size_t)(row + e) * 8192 + col] =
                    acc0[mf][nf][e] + acc1[mf][nf][e] * (1.f / 2048.f);
        }
}

// ---------------- merged gates: layer1(t) + layer0(t+1) in one pass ----------------
// Block = (i-tile of 64) x (one batch b). AHC cols b*128 + [l*64 + k].
// mode 0 (prologue): K-loop skipped (AHC=0), only layer-0 pointwise at t0.
// mode 1: acc1 over 4 chunks (W1T), acc0 over chunks 0-1 (W0T); epilogue updates
// H1/C1 then H0/C0 (x-path at t0); HT written directly as h4 (32B-coalesced runs).
__global__ __launch_bounds__(256) void gates_m(
    const float* __restrict__ AHC, int mode,
    const float* __restrict__ W1T, const float* __restrict__ W0T,
    const float* __restrict__ bh1, const float* __restrict__ bx1,
    const float* __restrict__ bh0, const float* __restrict__ bx0,
    const float* __restrict__ AX, const float* __restrict__ Wx0E, int t0,
    float* __restrict__ C1, float* __restrict__ C0,
    _Float16* __restrict__ HTh, _Float16* __restrict__ HTl)
{
    __shared__ float As[32][65];
    __shared__ float Bs[32 * 256];
    __shared__ float wx[512];
    const int tid = threadIdx.x;
    const int tx = tid & 15;
    const int ty = tid >> 4;
    const int i0 = (blockIdx.x >> 6) * 64;
    const int b  = blockIdx.x & 63;
    const int mrow = tid >> 3;          // 0..31
    const int f4i  = tid & 7;

    if (tid < 128) ((f4*)wx)[tid] = ((const f4*)Wx0E)[tid];

    f4 acc1[4][4], acc0[4][4];
    #pragma unroll
    for (int r = 0; r < 4; ++r)
        #pragma unroll
        for (int gq = 0; gq < 4; ++gq) {
            acc1[r][gq] = (f4){0.f, 0.f, 0.f, 0.f};
            acc0[r][gq] = (f4){0.f, 0.f, 0.f, 0.f};
        }

    if (mode) {
        for (int ch = 0; ch < 4; ++ch) {
            const int coff = b * 128 + ch * 32;
            f4 av0 = *(const f4*)&AHC[(size_t)(i0 + mrow) * 8192 + coff + f4i * 4];
            f4 av1 = *(const f4*)&AHC[(size_t)(i0 + mrow + 32) * 8192 + coff + f4i * 4];
            const float* wsrc = W1T + ch * 8192;
            f4 bv[8];
            #pragma unroll
            for (int r = 0; r < 8; ++r) bv[r] = *(const f4*)&wsrc[(tid + r * 256) * 4];
            __syncthreads();
            #pragma unroll
            for (int jj = 0; jj < 4; ++jj) {
                As[f4i * 4 + jj][mrow]      = av0[jj];
                As[f4i * 4 + jj][mrow + 32] = av1[jj];
            }
            #pragma unroll
            for (int r = 0; r < 8; ++r) *(f4*)&Bs[(tid + r * 256) * 4] = bv[r];
            __syncthreads();
            #pragma unroll
            for (int k = 0; k < 32; ++k) {
                float a[4];
                #pragma unroll
                for (int rr = 0; rr < 4; ++rr) a[rr] = As[k][ty * 4 + rr];
                f4 bq[4];
                #pragma unroll
                for (int gq = 0; gq < 4; ++gq) bq[gq] = *(const f4*)&Bs[k * 256 + gq * 64 + tx * 4];
                #pragma unroll
                for (int rr = 0; rr < 4; ++rr)
                    #pragma unroll
                    for (int gq = 0; gq < 4; ++gq)
                        acc1[rr][gq] += a[rr] * bq[gq];
            }
            if (ch < 2) {                       // layer-0 GEMM shares this A chunk
                const float* w0src = W0T + ch * 8192;
                f4 bw[8];
                #pragma unroll
                for (int r = 0; r < 8; ++r) bw[r] = *(const f4*)&w0src[(tid + r * 256) * 4];
                __syncthreads();
                #pragma unroll
                for (int r = 0; r < 8; ++r) *(f4*)&Bs[(tid + r * 256) * 4] = bw[r];
                __syncthreads();
                #pragma unroll
                for (int k = 0; k < 32; ++k) {
                    float a[4];
                    #pragma unroll
                    for (int rr = 0; rr < 4; ++rr) a[rr] = As[k][ty * 4 + rr];
                    f4 bq[4];
                    #pragma unroll
                    for (int gq = 0; gq < 4; ++gq) bq[gq] = *(const f4*)&Bs[k * 256 + gq * 64 + tx * 4];
                    #pragma unroll
                    for (int rr = 0; rr < 4; ++rr)
                        #pragma unroll
                        for (int gq = 0; gq < 4; ++gq)
                            acc0[rr][gq] += a[rr] * bq[gq];
                }
            }
        }
    }
    __syncthreads();                    // wx visible (mode 0 path has no earlier sync)

    f4 bb0[4], bb1[4];
    #pragma unroll
    for (int gq = 0; gq < 4; ++gq) {
        bb0[gq] = *(const f4*)&bh0[gq * 64 + tx * 4] + *(const f4*)&bx0[gq * 64 + tx * 4];
        bb1[gq] = *(const f4*)&bh1[gq * 64 + tx * 4] + *(const f4*)&bx1[gq * 64 + tx * 4];
    }

    f4 h1reg[4], h0reg[4];
    #pragma unroll
    for (int rr = 0; rr < 4; ++rr) {
        const int i = i0 + ty * 4 + rr;
        const bool valid = (i < 1000);
        f4 h1n = {0.f, 0.f, 0.f, 0.f};
        f4 h0n = {0.f, 0.f, 0.f, 0.f};
        if (mode && valid) {            // layer 1 update (time t)
            f4 gv[4];
            #pragma unroll
            for (int gq = 0; gq < 4; ++gq) gv[gq] = acc1[rr][gq] + bb1[gq];
            const size_t base = ((size_t)b * 1000 + i) * 64 + tx * 4;
            f4 cold = *(const f4*)&C1[base];
            f4 cnew;
            #pragma unroll
            for (int hh = 0; hh < 4; ++hh) {
                float ig = 1.f / (1.f + expf(-gv[0][hh]));
                float fg = 1.f / (1.f + expf(-gv[1][hh]));
                float og = 1.f / (1.f + expf(-gv[2][hh]));
                float gg = tanhf(gv[3][hh]);
                float c  = fg * cold[hh] + ig * gg;
                cnew[hh] = c;
                h1n[hh] = og * tanhf(c);
            }
            *(f4*)&C1[base] = cnew;
        }
        if (valid) {                    // layer 0 update (time t0)
            f4 gv[4];
            #pragma unroll
            for (int gq = 0; gq < 4; ++gq) gv[gq] = acc0[rr][gq] + bb0[gq];
            float x0 = AX[(size_t)i * 6144 + t0 * 128 + b * 2 + 0];
            float x1 = AX[(size_t)i * 6144 + t0 * 128 + b * 2 + 1];
            #pragma unroll
            for (int gq = 0; gq < 4; ++gq)
                #pragma unroll
                for (int hh = 0; hh < 4; ++hh) {
                    int gc = gq * 64 + tx * 4 + hh;
                    gv[gq][hh] = fmaf(x0, wx[gc * 2 + 0],
                                 fmaf(x1, wx[gc * 2 + 1], gv[gq][hh]));
                }
            const size_t base = ((size_t)b * 1000 + i) * 64 + tx * 4;
            f4 cold = *(const f4*)&C0[base];
            f4 cnew;
            #pragma unroll
            for (int hh = 0; hh < 4; ++hh) {
                float ig = 1.f / (1.f + expf(-gv[0][hh]));
                float fg = 1.f / (1.f + expf(-gv[1][hh]));
                float og = 1.f / (1.f + expf(-gv[2][hh]));
                float gg = tanhf(gv[3][hh]);
                float c  = fg * cold[hh] + ig * gg;
                cnew[hh] = c;
                h0n[hh] = og * tanhf(c);
            }
            *(f4*)&C0[base] = cnew;
        }
        h1reg[rr] = h1n;
        h0reg[rr] = h0n;
    }

    // direct HT writes: for each h (tx*4+hh), 4 consecutive i (rr) -> h4
    #pragma unroll
    for (int hh = 0; hh < 4; ++hh) {
        h4 vh0, vl0, vh1, vl1;
        #pragma unroll
        for (int rr = 0; rr < 4; ++rr) {
            float v0 = h0reg[rr][hh];
            _Float16 p0 = (_Float16)v0;
            vh0[rr] = p0; vl0[rr] = (_Float16)((v0 - (float)p0) * 2048.f);
            float v1 = h1reg[rr][hh];
            _Float16 p1 = (_Float16)v1;
            vh1[rr] = p1; vl1[rr] = (_Float16)((v1 - (float)p1) * 2048.f);
        }
        const size_t r0 = (size_t)(b * 128 + tx * 4 + hh) * 1024 + i0 + ty * 4;
        *(h4*)&HTh[r0] = vh0;
        *(h4*)&HTl[r0] = vl0;
        if (mode) {
            const size_t r1 = (size_t)(b * 128 + 64 + tx * 4 + hh) * 1024 + i0 + ty * 4;
            *(h4*)&HTh[r1] = vh1;
            *(h4*)&HTl[r1] = vl1;
        }
    }
}

// ---------------- final projection from HT layer-1 rows (n = b*128 + 64 + h) ----------------
__global__ __launch_bounds__(256) void proj_f16(const _Float16* __restrict__ HTh,
                                                const _Float16* __restrict__ HTl,
                                                const float* __restrict__ Wpj,
                                                const float* __restrict__ bp,
                                                float* __restrict__ out)
{
    int i = blockIdx.x * 256 + threadIdx.x;
    if (i >= 1000) return;
    int b = blockIdx.y;
    float hv[64];
    #pragma unroll
    for (int h = 0; h < 64; ++h) {
        size_t o = (size_t)(b * 128 + 64 + h) * 1024 + i;
        hv[h] = (float)HTh[o] + (float)HTl[o] * (1.f / 2048.f);
    }
    #pragma unroll
    for (int hor = 0; hor < 12; ++hor) {
        float s = bp[hor];
        #pragma unroll
        for (int h = 0; h < 64; ++h) s = fmaf(hv[h], Wpj[hor * 64 + h], s);
        out[(size_t)(b * 12 + hor) * 1000 + i] = s;
    }
}

extern "C" void kernel_launch(void* const* d_in, const int* in_sizes, int n_in,
                              void* d_out, int out_size, void* d_ws, size_t ws_size,
                              hipStream_t stream)
{
    const float* x   = (const float*)d_in[0];
    const float* E1  = (const float*)d_in[1];
    const float* E2  = (const float*)d_in[2];
    const float* Wx0 = (const float*)d_in[3];
    const float* bx0 = (const float*)d_in[4];
    const float* Wh0 = (const float*)d_in[5];
    const float* bh0 = (const float*)d_in[6];
    const float* Wx1 = (const float*)d_in[7];
    const float* bx1 = (const float*)d_in[8];
    const float* Wh1 = (const float*)d_in[9];
    const float* bh1 = (const float*)d_in[10];
    const float* Wp  = (const float*)d_in[11];
    const float* bp  = (const float*)d_in[12];
    float* out = (float*)d_out;
    float* ws  = (float*)d_ws;

    float*    AX  = ws + WS_AX;
    float*    AHC = ws + WS_AHC;
    float*    C0  = ws + WS_C0;
    float*    C1  = ws + WS_C1;
    _Float16* HTh = (_Float16*)(ws + WS_HTH);
    _Float16* HTl = (_Float16*)(ws + WS_HTL);
    _Float16* Ah  = (_Float16*)(ws + WS_A16H);
    _Float16* Al  = (_Float16*)(ws + WS_A16L);
    float*    W0T = ws + WS_W0T;
    float*    W1T = ws + WS_W1T;
    float*    At  = ws + WS_C0;    // alias: dead before C0/C1 zeroed
    float*    Xr  = ws + WS_AHC;   // alias: dead before AHC zeroed

    compute_A<<<1000, 256, 0, stream>>>(E1, E2, At);
    transpose_x<<<24000, 256, 0, stream>>>(x, Xr);
    gemm1000<<<dim3(16, 48), 256, 0, stream>>>(At, Xr, AX, 6144);   // AX = A @ Xr
    prep_w<<<192, 256, 0, stream>>>(Wh0, Wx1, Wh1, W0T, W1T);
    prep_A<<<4096, 256, 0, stream>>>(At, Ah, Al);
    zero_kernel<<<8000, 256, 0, stream>>>(ws + WS_C0, 2048000);     // C0,C1 (kills At)
    zero_kernel<<<8192, 256, 0, stream>>>(AHC, 2097152);            // AHC (kills Xr)
    zero_kernel<<<8192, 256, 0, stream>>>(ws + WS_HTH, 2097152);    // HTh,HTl

    // prologue: H0new(0) = pointwise(biases + x(0)), C0(0); (A@H0(-1) = 0)
    gates_m<<<1024, 256, 0, stream>>>(AHC, 0, W1T, W0T, bh1, bx1, bh0, bx0,
                                      AX, Wx0, 0, C1, C0, HTh, HTl);
    for (int t = 0; t < 48; ++t) {
        // AHC = A @ [H0new(t) | H1(t-1)]   (per-b interleaved columns)
        gemm_m<<<1024, 256, 0, stream>>>(Ah, Al, HTh, HTl, AHC);
        // layer1 update (t) + layer0 update (t+1); t=47's layer-0 output is unused
        gates_m<<<1024, 256, 0, stream>>>(AHC, 1, W1T, W0T, bh1, bx1, bh0, bx0,
                                          AX, Wx0, (t + 1) & 47, C1, C0, HTh, HTl);
    }
    proj_f16<<<dim3(4, 64), 256, 0, stream>>>(HTh, HTl, Wp, bp, out);
    (void)in_sizes; (void)n_in; (void)out_size; (void)ws_size;
}

// Round 12
// 8184.126 us; speedup vs baseline: 3.9559x; 3.9559x over previous
//
#include <hip/hip_runtime.h>
#include <math.h>

typedef float f4 __attribute__((ext_vector_type(4)));
typedef _Float16 h4 __attribute__((ext_vector_type(4)));
typedef _Float16 h8 __attribute__((ext_vector_type(8)));

// ---------------- workspace layout (float offsets), total 32,210,944 = 128.84 MB (R10-proven) ----
// AX  : A@x all t [i][t*128+b*2+c]      6,144,000
// AHC : A@[H0|H1] fp32 [1024][8192]     8,388,608   (Xr alias, dead before zero)
// C0,C1: cell state fp32 [b][1000][64]  2 x 4,096,000   (At alias in C0, dead before zero)
// HTh/l: [H0|H1]^T split f16 [8192][1024]  2 x 4,194,304
// Ah/Al: split f16 A [1024][1024]       2 x 524,288
// W0T [64][256], W1T [128][256] fp32
#define WS_AX    0
#define WS_AHC   6144000
#define WS_C0    14532608
#define WS_C1    18628608
#define WS_HTH   22724608
#define WS_HTL   26918912
#define WS_A16H  31113216
#define WS_A16L  31637504
#define WS_W0T   32161792
#define WS_W1T   32178176
// end = 32,210,944

// ---------------- A = softmax(relu(E1 @ E2^T)) in fp64, store A^T ----------------
__global__ __launch_bounds__(256) void compute_A(const float* __restrict__ E1,
                                                 const float* __restrict__ E2,
                                                 float* __restrict__ At)
{
    __shared__ double z[1000];
    __shared__ double red[256];
    __shared__ double e1[16];
    const int i = blockIdx.x;
    const int tid = threadIdx.x;
    if (tid < 16) e1[tid] = (double)E1[i * 16 + tid];
    __syncthreads();
    double lmax = -1e300;
    for (int j = tid; j < 1000; j += 256) {
        double s = 0.0;
        #pragma unroll
        for (int c = 0; c < 16; ++c) s += e1[c] * (double)E2[j * 16 + c];
        if (s < 0.0) s = 0.0;
        z[j] = s;
        if (s > lmax) lmax = s;
    }
    red[tid] = lmax; __syncthreads();
    for (int off = 128; off > 0; off >>= 1) {
        if (tid < off) red[tid] = fmax(red[tid], red[tid + off]);
        __syncthreads();
    }
    const double zmax = red[0];
    __syncthreads();
    double lsum = 0.0;
    for (int j = tid; j < 1000; j += 256) {
        double e = exp(z[j] - zmax);
        z[j] = e;
        lsum += e;
    }
    red[tid] = lsum; __syncthreads();
    for (int off = 128; off > 0; off >>= 1) {
        if (tid < off) red[tid] += red[tid + off];
        __syncthreads();
    }
    const double inv = 1.0 / red[0];
    for (int j = tid; j < 1000; j += 256)
        At[(size_t)j * 1000 + i] = (float)(z[j] * inv);
}

// ---------------- x [B,T,N,C] -> Xr [j][t*128 + b*2 + c] ----------------
__global__ __launch_bounds__(256) void transpose_x(const float* __restrict__ x,
                                                   float* __restrict__ Xr)
{
    int o = blockIdx.x * 256 + threadIdx.x;
    if (o >= 6144000) return;
    int j = o / 6144;
    int r = o - j * 6144;
    int t = r >> 7;
    int q = r & 127;
    int b = q >> 1;
    int c = q & 1;
    Xr[o] = x[(((size_t)(b * 48 + t)) * 1000 + j) * 2 + c];
}

__global__ __launch_bounds__(256) void zero_kernel(float* __restrict__ p, int n4)
{
    int i = blockIdx.x * 256 + threadIdx.x;
    if (i < n4) { f4 z = {0.f, 0.f, 0.f, 0.f}; ((f4*)p)[i] = z; }
}

// ---------------- weight transposes to [k][256] fp32 (once; R7-proven) ----------------
__global__ __launch_bounds__(256) void prep_w(const float* __restrict__ Wh0,
                                              const float* __restrict__ Wx1,
                                              const float* __restrict__ Wh1,
                                              float* __restrict__ W0T,
                                              float* __restrict__ W1T)
{
    int idx = blockIdx.x * 256 + threadIdx.x;
    if (idx < 16384) {
        int k = idx >> 8, o = idx & 255;
        W0T[idx] = Wh0[o * 64 + k];
    }
    int j = idx - 16384;
    if (j >= 0 && j < 32768) {
        int k = j >> 8, o = j & 255;
        W1T[j] = (k < 64) ? Wx1[o * 64 + k] : Wh1[o * 64 + (k - 64)];
    }
}

// ---------------- split A^T fp32 -> Ah/Al f16 [m=1024][k=1024] ----------------
__global__ __launch_bounds__(256) void prep_A(const float* __restrict__ At,
                                              _Float16* __restrict__ Ahh,
                                              _Float16* __restrict__ All)
{
    int idx = blockIdx.x * 256 + threadIdx.x;   // 1,048,576
    int m = idx >> 10, k = idx & 1023;
    float v = (m < 1000 && k < 1000) ? At[(size_t)k * 1000 + m] : 0.f;
    _Float16 hi = (_Float16)v;
    Ahh[idx] = hi;
    All[idx] = (_Float16)((v - (float)hi) * 2048.f);
}

// ---------------- fp32 GEMM (used once for AX; R1-proven) ----------------
__global__ __launch_bounds__(256) void gemm1000(const float* __restrict__ At,
                                                const float* __restrict__ B,
                                                float* __restrict__ C,
                                                int ncols)
{
    __shared__ float As[8][64];
    __shared__ float Bs[8][128];
    const int tid = threadIdx.x;
    const int tx = tid & 15;
    const int ty = tid >> 4;
    const int row0 = blockIdx.x * 64;
    const int col0 = blockIdx.y * 128;
    const int lm = tid & 63;
    const int lk = tid >> 6;
    const int bcol = tid & 127;
    const int bk = tid >> 7;
    const bool arow_ok = (row0 + lm) < 1000;

    float acc[4][8];
    #pragma unroll
    for (int r = 0; r < 4; ++r)
        #pragma unroll
        for (int c = 0; c < 8; ++c) acc[r][c] = 0.f;

    for (int k0 = 0; k0 < 1000; k0 += 8) {
        float a0 = arow_ok ? At[(size_t)(k0 + lk) * 1000 + row0 + lm] : 0.f;
        float a1 = arow_ok ? At[(size_t)(k0 + lk + 4) * 1000 + row0 + lm] : 0.f;
        float bv[4];
        #pragma unroll
        for (int kk = 0; kk < 4; ++kk)
            bv[kk] = B[(size_t)(k0 + bk * 4 + kk) * ncols + col0 + bcol];
        __syncthreads();
        As[lk][lm] = a0;
        As[lk + 4][lm] = a1;
        #pragma unroll
        for (int kk = 0; kk < 4; ++kk) Bs[bk * 4 + kk][bcol] = bv[kk];
        __syncthreads();
        #pragma unroll
        for (int k = 0; k < 8; ++k) {
            f4 av = *(const f4*)&As[k][ty * 4];
            f4 b0 = *(const f4*)&Bs[k][tx * 8];
            f4 b1 = *(const f4*)&Bs[k][tx * 8 + 4];
            #pragma unroll
            for (int r = 0; r < 4; ++r) {
                float a = av[r];
                acc[r][0] = fmaf(a, b0[0], acc[r][0]);
                acc[r][1] = fmaf(a, b0[1], acc[r][1]);
                acc[r][2] = fmaf(a, b0[2], acc[r][2]);
                acc[r][3] = fmaf(a, b0[3], acc[r][3]);
                acc[r][4] = fmaf(a, b1[0], acc[r][4]);
                acc[r][5] = fmaf(a, b1[1], acc[r][5]);
                acc[r][6] = fmaf(a, b1[2], acc[r][6]);
                acc[r][7] = fmaf(a, b1[3], acc[r][7]);
            }
        }
    }
    #pragma unroll
    for (int r = 0; r < 4; ++r) {
        int row = row0 + ty * 4 + r;
        if (row < 1000) {
            f4 o0 = {acc[r][0], acc[r][1], acc[r][2], acc[r][3]};
            f4 o1 = {acc[r][4], acc[r][5], acc[r][6], acc[r][7]};
            *(f4*)&C[(size_t)row * ncols + col0 + tx * 8]     = o0;
            *(f4*)&C[(size_t)row * ncols + col0 + tx * 8 + 4] = o1;
        }
    }
}

// ---------------- merged MFMA GEMM (R7 body + XCD mapping): AHC[1024][8192] = A @ HT^T ----------
// BM=64 BN=128 BK=32; grid 1024: xcd=bid&7 owns n-panels xcd*8..+8 (B-panels L2-local).
#define GL16(srcp, dstoff) \
    __builtin_amdgcn_global_load_lds((const __attribute__((address_space(1))) unsigned int*)(srcp), \
        (__attribute__((address_space(3))) unsigned int*)(lds + (dstoff)), 16, 0, 0)

__device__ __forceinline__ int swzb(int row, int lg) {
    return row * 64 + ((lg ^ ((row ^ (row >> 2)) & 3)) << 4);
}

__global__ __launch_bounds__(256, 2) void gemm_m(
    const _Float16* __restrict__ Ahg, const _Float16* __restrict__ Alg,
    const _Float16* __restrict__ Bhg, const _Float16* __restrict__ Blg,
    float* __restrict__ Cout)
{
    __shared__ __align__(1024) char lds[24576];
    const int tid = threadIdx.x;
    const int lane = tid & 63;
    const int w = tid >> 6;
    const int lg = lane >> 4, l15 = lane & 15;
    const int xcd = blockIdx.x & 7;
    const int j = blockIdx.x >> 3;
    const int m0 = (j >> 3) * 64;
    const int n0 = (xcd * 8 + (j & 7)) * 128;

    const int r16 = lane >> 2;
    const int sd = lane & 3;
    const char* src[6];
    #pragma unroll
    for (int q = 0; q < 6; ++q) {
        const int c = w * 6 + q;
        int row;
        const _Float16* g;
        if (c < 4)       { row = (c)      * 16 + r16; g = Ahg + (size_t)(m0 + row) * 1024; }
        else if (c < 8)  { row = (c - 4)  * 16 + r16; g = Alg + (size_t)(m0 + row) * 1024; }
        else if (c < 16) { row = (c - 8)  * 16 + r16; g = Bhg + (size_t)(n0 + row) * 1024; }
        else             { row = (c - 16) * 16 + r16; g = Blg + (size_t)(n0 + row) * 1024; }
        const int cg = sd ^ ((row ^ (row >> 2)) & 3);
        src[q] = (const char*)(g + cg * 8);
    }

    f4 acc0[4][2], acc1[4][2];
    #pragma unroll
    for (int a = 0; a < 4; ++a)
        #pragma unroll
        for (int b = 0; b < 2; ++b) {
            acc0[a][b] = (f4){0.f, 0.f, 0.f, 0.f};
            acc1[a][b] = (f4){0.f, 0.f, 0.f, 0.f};
        }

    for (int ks = 0; ks < 32; ++ks) {
        const int kadv = ks * 64;
        #pragma unroll
        for (int q = 0; q < 6; ++q)
            GL16(src[q] + kadv, (w * 6 + q) * 1024);
        __syncthreads();

        h8 fa[4], fl[4], bh[2], bl[2];
        #pragma unroll
        for (int mf = 0; mf < 4; ++mf) {
            const int ob = swzb(mf * 16 + l15, lg);
            fa[mf] = *(const h8*)(lds + ob);
            fl[mf] = *(const h8*)(lds + 4096 + ob);
        }
        #pragma unroll
        for (int nf = 0; nf < 2; ++nf) {
            const int ob = swzb(w * 32 + nf * 16 + l15, lg);
            bh[nf] = *(const h8*)(lds + 8192 + ob);
            bl[nf] = *(const h8*)(lds + 16384 + ob);
        }
        __syncthreads();

        #pragma unroll
        for (int nf = 0; nf < 2; ++nf)
            #pragma unroll
            for (int mf = 0; mf < 4; ++mf) {
                acc0[mf][nf] = __builtin_amdgcn_mfma_f32_16x16x32_f16(fa[mf], bh[nf], acc0[mf][nf], 0, 0, 0);
                acc1[mf][nf] = __builtin_amdgcn_mfma_f32_16x16x32_f16(fa[mf], bl[nf], acc1[mf][nf], 0, 0, 0);
                acc1[mf][nf] = __builtin_amdgcn_mfma_f32_16x16x32_f16(fl[mf], bh[nf], acc1[mf][nf], 0, 0, 0);
            }
    }

    #pragma unroll
    for (int mf = 0; mf < 4; ++mf)
        #pragma unroll
        for (int nf = 0; nf < 2; ++nf) {
            const int row = m0 + mf * 16 + lg * 4;
            const int col = n0 + w * 32 + nf * 16 + l15;
            #pragma unroll
            for (int e = 0; e < 4; ++e)
                Cout[(size_t)(row + e) * 8192 + col] =
                    acc0[mf][nf][e] + acc1[mf][nf][e] * (1.f / 2048.f);
        }
}

// ---------------- gates fused (R10-proven): fp32 core, i-blocked, HT^T epilogue ----
// Block = (i-tile of 64) x (one batch b): 1024 blocks. K=64 (two=0) or 128 (two=1).
// LDS phase 1: As[32][68] (16B-aligned rows -> ds_read_b128) + Bs[32*256] + wx = 43,520 B.
// LDS phase 2: Sh/Sl [64][80] f16 overlay on As/Bs region (wx untouched).
__global__ __launch_bounds__(256) void gates_f(
    const float* __restrict__ AHC, int two,
    const float* __restrict__ WT,
    const float* __restrict__ b1, const float* __restrict__ b2,
    const float* __restrict__ AX, const float* __restrict__ WxE, int t,
    float* __restrict__ Cst,
    _Float16* __restrict__ HTh, _Float16* __restrict__ HTl, int nbase)
{
    __shared__ __align__(16) char smem[43520];
    float (*As)[68] = (float(*)[68])smem;                 // 8,704 B
    float *Bs       = (float*)(smem + 8704);              // 32,768 B
    float *wx       = (float*)(smem + 41472);             // 2,048 B
    _Float16 (*Sh)[80] = (_Float16(*)[80])smem;           // 10,240 B (overlay)
    _Float16 (*Sl)[80] = (_Float16(*)[80])(smem + 10240); // 10,240 B (overlay, ends 20,480)
    const int tid = threadIdx.x;
    const int tx = tid & 15;
    const int ty = tid >> 4;
    const int i0 = (blockIdx.x >> 6) * 64;
    const int b  = blockIdx.x & 63;
    const int mrow = tid >> 3;          // 0..31
    const int f4i  = tid & 7;

    if (WxE && tid < 128) ((f4*)wx)[tid] = ((const f4*)WxE)[tid];

    f4 acc[4][4];
    #pragma unroll
    for (int r = 0; r < 4; ++r)
        #pragma unroll
        for (int gq = 0; gq < 4; ++gq) acc[r][gq] = (f4){0.f, 0.f, 0.f, 0.f};

    const int nchunk = two ? 4 : 2;
    for (int ch = 0; ch < nchunk; ++ch) {
        const int coff = ((ch < 2) ? 0 : 4096) + b * 64;
        const int koff = (ch & 1) * 32;
        f4 av0 = *(const f4*)&AHC[(size_t)(i0 + mrow) * 8192 + coff + koff + f4i * 4];
        f4 av1 = *(const f4*)&AHC[(size_t)(i0 + mrow + 32) * 8192 + coff + koff + f4i * 4];
        const float* wsrc = WT + ch * 8192;
        f4 bv[8];
        #pragma unroll
        for (int r = 0; r < 8; ++r) bv[r] = *(const f4*)&wsrc[(tid + r * 256) * 4];
        __syncthreads();
        #pragma unroll
        for (int j = 0; j < 4; ++j) {
            As[f4i * 4 + j][mrow]      = av0[j];
            As[f4i * 4 + j][mrow + 32] = av1[j];
        }
        #pragma unroll
        for (int r = 0; r < 8; ++r) *(f4*)&Bs[(tid + r * 256) * 4] = bv[r];
        __syncthreads();
        #pragma unroll
        for (int k = 0; k < 32; ++k) {
            f4 av = *(const f4*)&As[k][ty * 4];       // ds_read_b128 (16B-aligned)
            f4 bq[4];
            #pragma unroll
            for (int gq = 0; gq < 4; ++gq) bq[gq] = *(const f4*)&Bs[k * 256 + gq * 64 + tx * 4];
            #pragma unroll
            for (int rr = 0; rr < 4; ++rr)
                #pragma unroll
                for (int gq = 0; gq < 4; ++gq)
                    acc[rr][gq] += av[rr] * bq[gq];
        }
    }

    f4 bb[4];
    #pragma unroll
    for (int gq = 0; gq < 4; ++gq) {
        f4 v1 = *(const f4*)&b1[gq * 64 + tx * 4];
        f4 v2 = *(const f4*)&b2[gq * 64 + tx * 4];
        bb[gq] = v1 + v2;
    }

    f4 hreg[4];                          // [rr] -> H values for h = tx*4..+3
    #pragma unroll
    for (int rr = 0; rr < 4; ++rr) {
        const int i = i0 + ty * 4 + rr;
        const bool valid = (i < 1000);
        f4 gv[4];
        #pragma unroll
        for (int gq = 0; gq < 4; ++gq) gv[gq] = acc[rr][gq] + bb[gq];
        if (WxE && valid) {
            float x0 = AX[(size_t)i * 6144 + t * 128 + b * 2 + 0];
            float x1 = AX[(size_t)i * 6144 + t * 128 + b * 2 + 1];
            #pragma unroll
            for (int gq = 0; gq < 4; ++gq)
                #pragma unroll
                for (int hh = 0; hh < 4; ++hh) {
                    int gc = gq * 64 + tx * 4 + hh;
                    gv[gq][hh] = fmaf(x0, wx[gc * 2 + 0],
                                 fmaf(x1, wx[gc * 2 + 1], gv[gq][hh]));
                }
        }
        f4 hnew = {0.f, 0.f, 0.f, 0.f};
        if (valid) {
            const size_t base = ((size_t)b * 1000 + i) * 64 + tx * 4;
            f4 cold = *(const f4*)&Cst[base];
            f4 cnew;
            #pragma unroll
            for (int hh = 0; hh < 4; ++hh) {
                float ig = 1.f / (1.f + expf(-gv[0][hh]));
                float fg = 1.f / (1.f + expf(-gv[1][hh]));
                float og = 1.f / (1.f + expf(-gv[2][hh]));
                float gg = tanhf(gv[3][hh]);
                float c  = fg * cold[hh] + ig * gg;
                cnew[hh] = c;
                hnew[hh] = og * tanhf(c);
            }
            *(f4*)&Cst[base] = cnew;
        }
        hreg[rr] = hnew;
    }

    __syncthreads();                     // all As/Bs/wx reads done before overlay writes
    #pragma unroll
    for (int hh = 0; hh < 4; ++hh) {
        h4 vh, vl;
        #pragma unroll
        for (int rr = 0; rr < 4; ++rr) {
            float v = hreg[rr][hh];
            _Float16 hi = (_Float16)v;
            vh[rr] = hi;
            vl[rr] = (_Float16)((v - (float)hi) * 2048.f);
        }
        *(h4*)&Sh[tx * 4 + hh][ty * 4] = vh;
        *(h4*)&Sl[tx * 4 + hh][ty * 4] = vl;
    }
    __syncthreads();
    // coalesced writeout: HT[n = nbase + b*64 + h][i0 .. i0+64)
    #pragma unroll
    for (int pass = 0; pass < 2; ++pass) {
        const int c = pass * 256 + tid;          // 0..511
        const int row = c >> 3;                  // h
        const int off = (c & 7) * 8;             // i-local, 8-aligned
        const size_t go = (size_t)(nbase + b * 64 + row) * 1024 + i0 + off;
        *(h8*)&HTh[go] = *(const h8*)&Sh[row][off];
        *(h8*)&HTl[go] = *(const h8*)&Sl[row][off];
    }
}

// ---------------- final projection from HT rows 4096: (H1^T split f16) ----------------
__global__ __launch_bounds__(256) void proj_f16(const _Float16* __restrict__ HTh,
                                                const _Float16* __restrict__ HTl,
                                                const float* __restrict__ Wpj,
                                                const float* __restrict__ bp,
                                                float* __restrict__ out)
{
    int i = blockIdx.x * 256 + threadIdx.x;
    if (i >= 1000) return;
    int b = blockIdx.y;
    float hv[64];
    #pragma unroll
    for (int h = 0; h < 64; ++h) {
        size_t o = (size_t)(4096 + b * 64 + h) * 1024 + i;
        hv[h] = (float)HTh[o] + (float)HTl[o] * (1.f / 2048.f);
    }
    #pragma unroll
    for (int hor = 0; hor < 12; ++hor) {
        float s = bp[hor];
        #pragma unroll
        for (int h = 0; h < 64; ++h) s = fmaf(hv[h], Wpj[hor * 64 + h], s);
        out[(size_t)(b * 12 + hor) * 1000 + i] = s;
    }
}

extern "C" void kernel_launch(void* const* d_in, const int* in_sizes, int n_in,
                              void* d_out, int out_size, void* d_ws, size_t ws_size,
                              hipStream_t stream)
{
    const float* x   = (const float*)d_in[0];
    const float* E1  = (const float*)d_in[1];
    const float* E2  = (const float*)d_in[2];
    const float* Wx0 = (const float*)d_in[3];
    const float* bx0 = (const float*)d_in[4];
    const float* Wh0 = (const float*)d_in[5];
    const float* bh0 = (const float*)d_in[6];
    const float* Wx1 = (const float*)d_in[7];
    const float* bx1 = (const float*)d_in[8];
    const float* Wh1 = (const float*)d_in[9];
    const float* bh1 = (const float*)d_in[10];
    const float* Wp  = (const float*)d_in[11];
    const float* bp  = (const float*)d_in[12];
    float* out = (float*)d_out;
    float* ws  = (float*)d_ws;

    float*    AX  = ws + WS_AX;
    float*    AHC = ws + WS_AHC;
    float*    C0  = ws + WS_C0;
    float*    C1  = ws + WS_C1;
    _Float16* HTh = (_Float16*)(ws + WS_HTH);
    _Float16* HTl = (_Float16*)(ws + WS_HTL);
    _Float16* Ah  = (_Float16*)(ws + WS_A16H);
    _Float16* Al  = (_Float16*)(ws + WS_A16L);
    float*    W0T = ws + WS_W0T;
    float*    W1T = ws + WS_W1T;
    float*    At  = ws + WS_C0;    // alias: dead before C0/C1 zeroed
    float*    Xr  = ws + WS_AHC;   // alias: dead before AHC zeroed

    compute_A<<<1000, 256, 0, stream>>>(E1, E2, At);
    transpose_x<<<24000, 256, 0, stream>>>(x, Xr);
    gemm1000<<<dim3(16, 48), 256, 0, stream>>>(At, Xr, AX, 6144);   // AX = A @ Xr
    prep_w<<<192, 256, 0, stream>>>(Wh0, Wx1, Wh1, W0T, W1T);
    prep_A<<<4096, 256, 0, stream>>>(At, Ah, Al);
    zero_kernel<<<8000, 256, 0, stream>>>(ws + WS_C0, 2048000);     // C0,C1 (kills At)
    zero_kernel<<<8192, 256, 0, stream>>>(AHC, 2097152);            // AHC (kills Xr)
    zero_kernel<<<8192, 256, 0, stream>>>(ws + WS_HTH, 2097152);    // HTh,HTl (H init = 0)

    for (int t = 0; t < 48; ++t) {
        // layer 0: gates = (A@H0prev)[cols 0:4096] Wh0^T + x-path -> C0, HT rows 0:4096
        gates_f<<<1024, 256, 0, stream>>>(AHC, 0, W0T, bh0, bx0,
                                          AX, Wx0, t, C0, HTh, HTl, 0);
        // AHC = A @ [H0new | H1prev]  (HT rows 4096: hold H1new(t-1))
        gemm_m<<<1024, 256, 0, stream>>>(Ah, Al, HTh, HTl, AHC);
        // layer 1: gates = (A@H0new)Wx1^T + (A@H1prev)Wh1^T -> C1, HT rows 4096:
        gates_f<<<1024, 256, 0, stream>>>(AHC, 1, W1T, bh1, bx1,
                                          nullptr, nullptr, 0, C1, HTh, HTl, 4096);
    }
    proj_f16<<<dim3(4, 64), 256, 0, stream>>>(HTh, HTl, Wp, bp, out);
    (void)in_sizes; (void)n_in; (void)out_size; (void)ws_size;
}

// Round 13
// 8039.229 us; speedup vs baseline: 4.0272x; 1.0180x over previous
//
#include <hip/hip_runtime.h>
#include <math.h>

typedef float f4 __attribute__((ext_vector_type(4)));
typedef _Float16 h4 __attribute__((ext_vector_type(4)));
typedef _Float16 h8 __attribute__((ext_vector_type(8)));

// ---------------- workspace layout (float offsets), total 32,210,944 = 128.84 MB (R10-proven) ----
// AX  : A@x all t [i][t*128+b*2+c]      6,144,000
// AHC : A@[H0|H1] fp32 [1024][8192]     8,388,608   (Xr alias, dead before zero)
// C0,C1: cell state fp32 [b][1000][64]  2 x 4,096,000   (At alias in C0, dead before zero)
// HTh/l: [H0|H1]^T split f16 [8192][1024]  2 x 4,194,304
// Ah/Al: split f16 A [1024][1024]       2 x 524,288
// W0T [64][256], W1T [128][256] fp32
#define WS_AX    0
#define WS_AHC   6144000
#define WS_C0    14532608
#define WS_C1    18628608
#define WS_HTH   22724608
#define WS_HTL   26918912
#define WS_A16H  31113216
#define WS_A16L  31637504
#define WS_W0T   32161792
#define WS_W1T   32178176
// end = 32,210,944

// ---------------- A = softmax(relu(E1 @ E2^T)) in fp64, store A^T ----------------
__global__ __launch_bounds__(256) void compute_A(const float* __restrict__ E1,
                                                 const float* __restrict__ E2,
                                                 float* __restrict__ At)
{
    __shared__ double z[1000];
    __shared__ double red[256];
    __shared__ double e1[16];
    const int i = blockIdx.x;
    const int tid = threadIdx.x;
    if (tid < 16) e1[tid] = (double)E1[i * 16 + tid];
    __syncthreads();
    double lmax = -1e300;
    for (int j = tid; j < 1000; j += 256) {
        double s = 0.0;
        #pragma unroll
        for (int c = 0; c < 16; ++c) s += e1[c] * (double)E2[j * 16 + c];
        if (s < 0.0) s = 0.0;
        z[j] = s;
        if (s > lmax) lmax = s;
    }
    red[tid] = lmax; __syncthreads();
    for (int off = 128; off > 0; off >>= 1) {
        if (tid < off) red[tid] = fmax(red[tid], red[tid + off]);
        __syncthreads();
    }
    const double zmax = red[0];
    __syncthreads();
    double lsum = 0.0;
    for (int j = tid; j < 1000; j += 256) {
        double e = exp(z[j] - zmax);
        z[j] = e;
        lsum += e;
    }
    red[tid] = lsum; __syncthreads();
    for (int off = 128; off > 0; off >>= 1) {
        if (tid < off) red[tid] += red[tid + off];
        __syncthreads();
    }
    const double inv = 1.0 / red[0];
    for (int j = tid; j < 1000; j += 256)
        At[(size_t)j * 1000 + i] = (float)(z[j] * inv);
}

// ---------------- x [B,T,N,C] -> Xr [j][t*128 + b*2 + c] ----------------
__global__ __launch_bounds__(256) void transpose_x(const float* __restrict__ x,
                                                   float* __restrict__ Xr)
{
    int o = blockIdx.x * 256 + threadIdx.x;
    if (o >= 6144000) return;
    int j = o / 6144;
    int r = o - j * 6144;
    int t = r >> 7;
    int q = r & 127;
    int b = q >> 1;
    int c = q & 1;
    Xr[o] = x[(((size_t)(b * 48 + t)) * 1000 + j) * 2 + c];
}

__global__ __launch_bounds__(256) void zero_kernel(float* __restrict__ p, int n4)
{
    int i = blockIdx.x * 256 + threadIdx.x;
    if (i < n4) { f4 z = {0.f, 0.f, 0.f, 0.f}; ((f4*)p)[i] = z; }
}

// ---------------- weight transposes to [k][256] fp32 (once; R7-proven) ----------------
__global__ __launch_bounds__(256) void prep_w(const float* __restrict__ Wh0,
                                              const float* __restrict__ Wx1,
                                              const float* __restrict__ Wh1,
                                              float* __restrict__ W0T,
                                              float* __restrict__ W1T)
{
    int idx = blockIdx.x * 256 + threadIdx.x;
    if (idx < 16384) {
        int k = idx >> 8, o = idx & 255;
        W0T[idx] = Wh0[o * 64 + k];
    }
    int j = idx - 16384;
    if (j >= 0 && j < 32768) {
        int k = j >> 8, o = j & 255;
        W1T[j] = (k < 64) ? Wx1[o * 64 + k] : Wh1[o * 64 + (k - 64)];
    }
}

// ---------------- split A^T fp32 -> Ah/Al f16 [m=1024][k=1024] ----------------
__global__ __launch_bounds__(256) void prep_A(const float* __restrict__ At,
                                              _Float16* __restrict__ Ahh,
                                              _Float16* __restrict__ All)
{
    int idx = blockIdx.x * 256 + threadIdx.x;   // 1,048,576
    int m = idx >> 10, k = idx & 1023;
    float v = (m < 1000 && k < 1000) ? At[(size_t)k * 1000 + m] : 0.f;
    _Float16 hi = (_Float16)v;
    Ahh[idx] = hi;
    All[idx] = (_Float16)((v - (float)hi) * 2048.f);
}

// ---------------- fp32 GEMM (used once for AX; R1-proven) ----------------
__global__ __launch_bounds__(256) void gemm1000(const float* __restrict__ At,
                                                const float* __restrict__ B,
                                                float* __restrict__ C,
                                                int ncols)
{
    __shared__ float As[8][64];
    __shared__ float Bs[8][128];
    const int tid = threadIdx.x;
    const int tx = tid & 15;
    const int ty = tid >> 4;
    const int row0 = blockIdx.x * 64;
    const int col0 = blockIdx.y * 128;
    const int lm = tid & 63;
    const int lk = tid >> 6;
    const int bcol = tid & 127;
    const int bk = tid >> 7;
    const bool arow_ok = (row0 + lm) < 1000;

    float acc[4][8];
    #pragma unroll
    for (int r = 0; r < 4; ++r)
        #pragma unroll
        for (int c = 0; c < 8; ++c) acc[r][c] = 0.f;

    for (int k0 = 0; k0 < 1000; k0 += 8) {
        float a0 = arow_ok ? At[(size_t)(k0 + lk) * 1000 + row0 + lm] : 0.f;
        float a1 = arow_ok ? At[(size_t)(k0 + lk + 4) * 1000 + row0 + lm] : 0.f;
        float bv[4];
        #pragma unroll
        for (int kk = 0; kk < 4; ++kk)
            bv[kk] = B[(size_t)(k0 + bk * 4 + kk) * ncols + col0 + bcol];
        __syncthreads();
        As[lk][lm] = a0;
        As[lk + 4][lm] = a1;
        #pragma unroll
        for (int kk = 0; kk < 4; ++kk) Bs[bk * 4 + kk][bcol] = bv[kk];
        __syncthreads();
        #pragma unroll
        for (int k = 0; k < 8; ++k) {
            f4 av = *(const f4*)&As[k][ty * 4];
            f4 b0 = *(const f4*)&Bs[k][tx * 8];
            f4 b1 = *(const f4*)&Bs[k][tx * 8 + 4];
            #pragma unroll
            for (int r = 0; r < 4; ++r) {
                float a = av[r];
                acc[r][0] = fmaf(a, b0[0], acc[r][0]);
                acc[r][1] = fmaf(a, b0[1], acc[r][1]);
                acc[r][2] = fmaf(a, b0[2], acc[r][2]);
                acc[r][3] = fmaf(a, b0[3], acc[r][3]);
                acc[r][4] = fmaf(a, b1[0], acc[r][4]);
                acc[r][5] = fmaf(a, b1[1], acc[r][5]);
                acc[r][6] = fmaf(a, b1[2], acc[r][6]);
                acc[r][7] = fmaf(a, b1[3], acc[r][7]);
            }
        }
    }
    #pragma unroll
    for (int r = 0; r < 4; ++r) {
        int row = row0 + ty * 4 + r;
        if (row < 1000) {
            f4 o0 = {acc[r][0], acc[r][1], acc[r][2], acc[r][3]};
            f4 o1 = {acc[r][4], acc[r][5], acc[r][6], acc[r][7]};
            *(f4*)&C[(size_t)row * ncols + col0 + tx * 8]     = o0;
            *(f4*)&C[(size_t)row * ncols + col0 + tx * 8 + 4] = o1;
        }
    }
}

// ---------------- merged MFMA GEMM (R12-proven): AHC[1024][8192] = A @ HT^T ----------
// BM=64 BN=128 BK=32; grid 1024: xcd=bid&7 owns n-panels xcd*8..+8 (B-panels L2-local).
#define GL16(srcp, dstoff) \
    __builtin_amdgcn_global_load_lds((const __attribute__((address_space(1))) unsigned int*)(srcp), \
        (__attribute__((address_space(3))) unsigned int*)(lds + (dstoff)), 16, 0, 0)

__device__ __forceinline__ int swzb(int row, int lg) {
    return row * 64 + ((lg ^ ((row ^ (row >> 2)) & 3)) << 4);
}

__global__ __launch_bounds__(256, 2) void gemm_m(
    const _Float16* __restrict__ Ahg, const _Float16* __restrict__ Alg,
    const _Float16* __restrict__ Bhg, const _Float16* __restrict__ Blg,
    float* __restrict__ Cout)
{
    __shared__ __align__(1024) char lds[24576];
    const int tid = threadIdx.x;
    const int lane = tid & 63;
    const int w = tid >> 6;
    const int lg = lane >> 4, l15 = lane & 15;
    const int xcd = blockIdx.x & 7;
    const int j = blockIdx.x >> 3;
    const int m0 = (j >> 3) * 64;
    const int n0 = (xcd * 8 + (j & 7)) * 128;

    const int r16 = lane >> 2;
    const int sd = lane & 3;
    const char* src[6];
    #pragma unroll
    for (int q = 0; q < 6; ++q) {
        const int c = w * 6 + q;
        int row;
        const _Float16* g;
        if (c < 4)       { row = (c)      * 16 + r16; g = Ahg + (size_t)(m0 + row) * 1024; }
        else if (c < 8)  { row = (c - 4)  * 16 + r16; g = Alg + (size_t)(m0 + row) * 1024; }
        else if (c < 16) { row = (c - 8)  * 16 + r16; g = Bhg + (size_t)(n0 + row) * 1024; }
        else             { row = (c - 16) * 16 + r16; g = Blg + (size_t)(n0 + row) * 1024; }
        const int cg = sd ^ ((row ^ (row >> 2)) & 3);
        src[q] = (const char*)(g + cg * 8);
    }

    f4 acc0[4][2], acc1[4][2];
    #pragma unroll
    for (int a = 0; a < 4; ++a)
        #pragma unroll
        for (int b = 0; b < 2; ++b) {
            acc0[a][b] = (f4){0.f, 0.f, 0.f, 0.f};
            acc1[a][b] = (f4){0.f, 0.f, 0.f, 0.f};
        }

    for (int ks = 0; ks < 32; ++ks) {
        const int kadv = ks * 64;
        #pragma unroll
        for (int q = 0; q < 6; ++q)
            GL16(src[q] + kadv, (w * 6 + q) * 1024);
        __syncthreads();

        h8 fa[4], fl[4], bh[2], bl[2];
        #pragma unroll
        for (int mf = 0; mf < 4; ++mf) {
            const int ob = swzb(mf * 16 + l15, lg);
            fa[mf] = *(const h8*)(lds + ob);
            fl[mf] = *(const h8*)(lds + 4096 + ob);
        }
        #pragma unroll
        for (int nf = 0; nf < 2; ++nf) {
            const int ob = swzb(w * 32 + nf * 16 + l15, lg);
            bh[nf] = *(const h8*)(lds + 8192 + ob);
            bl[nf] = *(const h8*)(lds + 16384 + ob);
        }
        __syncthreads();

        #pragma unroll
        for (int nf = 0; nf < 2; ++nf)
            #pragma unroll
            for (int mf = 0; mf < 4; ++mf) {
                acc0[mf][nf] = __builtin_amdgcn_mfma_f32_16x16x32_f16(fa[mf], bh[nf], acc0[mf][nf], 0, 0, 0);
                acc1[mf][nf] = __builtin_amdgcn_mfma_f32_16x16x32_f16(fa[mf], bl[nf], acc1[mf][nf], 0, 0, 0);
                acc1[mf][nf] = __builtin_amdgcn_mfma_f32_16x16x32_f16(fl[mf], bh[nf], acc1[mf][nf], 0, 0, 0);
            }
    }

    #pragma unroll
    for (int mf = 0; mf < 4; ++mf)
        #pragma unroll
        for (int nf = 0; nf < 2; ++nf) {
            const int row = m0 + mf * 16 + lg * 4;
            const int col = n0 + w * 32 + nf * 16 + l15;
            #pragma unroll
            for (int e = 0; e < 4; ++e)
                Cout[(size_t)(row + e) * 8192 + col] =
                    acc0[mf][nf][e] + acc1[mf][nf][e] * (1.f / 2048.f);
        }
}

// ---------------- combined gates (R12 body, grid-level layer merge) ----------------
// Grid 2048: blocks 0..1023 = layer1(t)  (two=1, W1T, -> C1, HT rows 4096:)
//            blocks 1024..2047 = layer0(t+1) (two=0, W0T, x-path, -> C0, HT rows 0:4096)
// The two halves are data-independent: both only READ AHC; writes are disjoint.
// Per-block footprint identical to R12's gates_f (43.5 KB LDS, same VGPR).
__global__ __launch_bounds__(256) void gates_c(
    const float* __restrict__ AHC,
    const float* __restrict__ W1T, const float* __restrict__ W0T,
    const float* __restrict__ bh1, const float* __restrict__ bx1,
    const float* __restrict__ bh0, const float* __restrict__ bx0,
    const float* __restrict__ AX, const float* __restrict__ Wx0E, int tnext,
    float* __restrict__ C1, float* __restrict__ C0,
    _Float16* __restrict__ HTh, _Float16* __restrict__ HTl)
{
    __shared__ __align__(16) char smem[43520];
    float (*As)[68] = (float(*)[68])smem;                 // 8,704 B
    float *Bs       = (float*)(smem + 8704);              // 32,768 B
    float *wx       = (float*)(smem + 41472);             // 2,048 B
    _Float16 (*Sh)[80] = (_Float16(*)[80])smem;           // 10,240 B (overlay)
    _Float16 (*Sl)[80] = (_Float16(*)[80])(smem + 10240); // 10,240 B (overlay)

    const int half = blockIdx.x >> 10;       // 0 = layer1(t), 1 = layer0(t+1)
    const int bidx = blockIdx.x & 1023;
    const int two  = half ^ 1;
    const float* WT  = half ? W0T : W1T;
    const float* b1  = half ? bh0 : bh1;
    const float* b2  = half ? bx0 : bx1;
    const float* WxE = half ? Wx0E : nullptr;
    float* Cst = half ? C0 : C1;
    const int nbase = half ? 0 : 4096;
    const int t = tnext;

    const int tid = threadIdx.x;
    const int tx = tid & 15;
    const int ty = tid >> 4;
    const int i0 = (bidx >> 6) * 64;
    const int b  = bidx & 63;
    const int mrow = tid >> 3;          // 0..31
    const int f4i  = tid & 7;

    if (WxE && tid < 128) ((f4*)wx)[tid] = ((const f4*)WxE)[tid];

    f4 acc[4][4];
    #pragma unroll
    for (int r = 0; r < 4; ++r)
        #pragma unroll
        for (int gq = 0; gq < 4; ++gq) acc[r][gq] = (f4){0.f, 0.f, 0.f, 0.f};

    const int nchunk = two ? 4 : 2;
    for (int ch = 0; ch < nchunk; ++ch) {
        const int coff = ((ch < 2) ? 0 : 4096) + b * 64;
        const int koff = (ch & 1) * 32;
        f4 av0 = *(const f4*)&AHC[(size_t)(i0 + mrow) * 8192 + coff + koff + f4i * 4];
        f4 av1 = *(const f4*)&AHC[(size_t)(i0 + mrow + 32) * 8192 + coff + koff + f4i * 4];
        const float* wsrc = WT + ch * 8192;
        f4 bv[8];
        #pragma unroll
        for (int r = 0; r < 8; ++r) bv[r] = *(const f4*)&wsrc[(tid + r * 256) * 4];
        __syncthreads();
        #pragma unroll
        for (int j = 0; j < 4; ++j) {
            As[f4i * 4 + j][mrow]      = av0[j];
            As[f4i * 4 + j][mrow + 32] = av1[j];
        }
        #pragma unroll
        for (int r = 0; r < 8; ++r) *(f4*)&Bs[(tid + r * 256) * 4] = bv[r];
        __syncthreads();
        #pragma unroll
        for (int k = 0; k < 32; ++k) {
            f4 av = *(const f4*)&As[k][ty * 4];       // ds_read_b128
            f4 bq[4];
            #pragma unroll
            for (int gq = 0; gq < 4; ++gq) bq[gq] = *(const f4*)&Bs[k * 256 + gq * 64 + tx * 4];
            #pragma unroll
            for (int rr = 0; rr < 4; ++rr)
                #pragma unroll
                for (int gq = 0; gq < 4; ++gq)
                    acc[rr][gq] += av[rr] * bq[gq];
        }
    }

    f4 bb[4];
    #pragma unroll
    for (int gq = 0; gq < 4; ++gq) {
        f4 v1 = *(const f4*)&b1[gq * 64 + tx * 4];
        f4 v2 = *(const f4*)&b2[gq * 64 + tx * 4];
        bb[gq] = v1 + v2;
    }

    f4 hreg[4];
    #pragma unroll
    for (int rr = 0; rr < 4; ++rr) {
        const int i = i0 + ty * 4 + rr;
        const bool valid = (i < 1000);
        f4 gv[4];
        #pragma unroll
        for (int gq = 0; gq < 4; ++gq) gv[gq] = acc[rr][gq] + bb[gq];
        if (WxE && valid) {
            float x0 = AX[(size_t)i * 6144 + t * 128 + b * 2 + 0];
            float x1 = AX[(size_t)i * 6144 + t * 128 + b * 2 + 1];
            #pragma unroll
            for (int gq = 0; gq < 4; ++gq)
                #pragma unroll
                for (int hh = 0; hh < 4; ++hh) {
                    int gc = gq * 64 + tx * 4 + hh;
                    gv[gq][hh] = fmaf(x0, wx[gc * 2 + 0],
                                 fmaf(x1, wx[gc * 2 + 1], gv[gq][hh]));
                }
        }
        f4 hnew = {0.f, 0.f, 0.f, 0.f};
        if (valid) {
            const size_t base = ((size_t)b * 1000 + i) * 64 + tx * 4;
            f4 cold = *(const f4*)&Cst[base];
            f4 cnew;
            #pragma unroll
            for (int hh = 0; hh < 4; ++hh) {
                float ig = 1.f / (1.f + expf(-gv[0][hh]));
                float fg = 1.f / (1.f + expf(-gv[1][hh]));
                float og = 1.f / (1.f + expf(-gv[2][hh]));
                float gg = tanhf(gv[3][hh]);
                float c  = fg * cold[hh] + ig * gg;
                cnew[hh] = c;
                hnew[hh] = og * tanhf(c);
            }
            *(f4*)&Cst[base] = cnew;
        }
        hreg[rr] = hnew;
    }

    __syncthreads();
    #pragma unroll
    for (int hh = 0; hh < 4; ++hh) {
        h4 vh, vl;
        #pragma unroll
        for (int rr = 0; rr < 4; ++rr) {
            float v = hreg[rr][hh];
            _Float16 hi = (_Float16)v;
            vh[rr] = hi;
            vl[rr] = (_Float16)((v - (float)hi) * 2048.f);
        }
        *(h4*)&Sh[tx * 4 + hh][ty * 4] = vh;
        *(h4*)&Sl[tx * 4 + hh][ty * 4] = vl;
    }
    __syncthreads();
    #pragma unroll
    for (int pass = 0; pass < 2; ++pass) {
        const int c = pass * 256 + tid;
        const int row = c >> 3;
        const int off = (c & 7) * 8;
        const size_t go = (size_t)(nbase + b * 64 + row) * 1024 + i0 + off;
        *(h8*)&HTh[go] = *(const h8*)&Sh[row][off];
        *(h8*)&HTl[go] = *(const h8*)&Sl[row][off];
    }
}

// ---------------- prologue gates (R12-proven gates_f, layer-0 only, AHC=0) ----------------
__global__ __launch_bounds__(256) void gates_f(
    const float* __restrict__ AHC, int two,
    const float* __restrict__ WT,
    const float* __restrict__ b1, const float* __restrict__ b2,
    const float* __restrict__ AX, const float* __restrict__ WxE, int t,
    float* __restrict__ Cst,
    _Float16* __restrict__ HTh, _Float16* __restrict__ HTl, int nbase)
{
    __shared__ __align__(16) char smem[43520];
    float (*As)[68] = (float(*)[68])smem;
    float *Bs       = (float*)(smem + 8704);
    float *wx       = (float*)(smem + 41472);
    _Float16 (*Sh)[80] = (_Float16(*)[80])smem;
    _Float16 (*Sl)[80] = (_Float16(*)[80])(smem + 10240);
    const int tid = threadIdx.x;
    const int tx = tid & 15;
    const int ty = tid >> 4;
    const int i0 = (blockIdx.x >> 6) * 64;
    const int b  = blockIdx.x & 63;
    const int mrow = tid >> 3;
    const int f4i  = tid & 7;

    if (WxE && tid < 128) ((f4*)wx)[tid] = ((const f4*)WxE)[tid];

    f4 acc[4][4];
    #pragma unroll
    for (int r = 0; r < 4; ++r)
        #pragma unroll
        for (int gq = 0; gq < 4; ++gq) acc[r][gq] = (f4){0.f, 0.f, 0.f, 0.f};

    const int nchunk = two ? 4 : 2;
    for (int ch = 0; ch < nchunk; ++ch) {
        const int coff = ((ch < 2) ? 0 : 4096) + b * 64;
        const int koff = (ch & 1) * 32;
        f4 av0 = *(const f4*)&AHC[(size_t)(i0 + mrow) * 8192 + coff + koff + f4i * 4];
        f4 av1 = *(const f4*)&AHC[(size_t)(i0 + mrow + 32) * 8192 + coff + koff + f4i * 4];
        const float* wsrc = WT + ch * 8192;
        f4 bv[8];
        #pragma unroll
        for (int r = 0; r < 8; ++r) bv[r] = *(const f4*)&wsrc[(tid + r * 256) * 4];
        __syncthreads();
        #pragma unroll
        for (int j = 0; j < 4; ++j) {
            As[f4i * 4 + j][mrow]      = av0[j];
            As[f4i * 4 + j][mrow + 32] = av1[j];
        }
        #pragma unroll
        for (int r = 0; r < 8; ++r) *(f4*)&Bs[(tid + r * 256) * 4] = bv[r];
        __syncthreads();
        #pragma unroll
        for (int k = 0; k < 32; ++k) {
            f4 av = *(const f4*)&As[k][ty * 4];
            f4 bq[4];
            #pragma unroll
            for (int gq = 0; gq < 4; ++gq) bq[gq] = *(const f4*)&Bs[k * 256 + gq * 64 + tx * 4];
            #pragma unroll
            for (int rr = 0; rr < 4; ++rr)
                #pragma unroll
                for (int gq = 0; gq < 4; ++gq)
                    acc[rr][gq] += av[rr] * bq[gq];
        }
    }

    f4 bb[4];
    #pragma unroll
    for (int gq = 0; gq < 4; ++gq) {
        f4 v1 = *(const f4*)&b1[gq * 64 + tx * 4];
        f4 v2 = *(const f4*)&b2[gq * 64 + tx * 4];
        bb[gq] = v1 + v2;
    }

    f4 hreg[4];
    #pragma unroll
    for (int rr = 0; rr < 4; ++rr) {
        const int i = i0 + ty * 4 + rr;
        const bool valid = (i < 1000);
        f4 gv[4];
        #pragma unroll
        for (int gq = 0; gq < 4; ++gq) gv[gq] = acc[rr][gq] + bb[gq];
        if (WxE && valid) {
            float x0 = AX[(size_t)i * 6144 + t * 128 + b * 2 + 0];
            float x1 = AX[(size_t)i * 6144 + t * 128 + b * 2 + 1];
            #pragma unroll
            for (int gq = 0; gq < 4; ++gq)
                #pragma unroll
                for (int hh = 0; hh < 4; ++hh) {
                    int gc = gq * 64 + tx * 4 + hh;
                    gv[gq][hh] = fmaf(x0, wx[gc * 2 + 0],
                                 fmaf(x1, wx[gc * 2 + 1], gv[gq][hh]));
                }
        }
        f4 hnew = {0.f, 0.f, 0.f, 0.f};
        if (valid) {
            const size_t base = ((size_t)b * 1000 + i) * 64 + tx * 4;
            f4 cold = *(const f4*)&Cst[base];
            f4 cnew;
            #pragma unroll
            for (int hh = 0; hh < 4; ++hh) {
                float ig = 1.f / (1.f + expf(-gv[0][hh]));
                float fg = 1.f / (1.f + expf(-gv[1][hh]));
                float og = 1.f / (1.f + expf(-gv[2][hh]));
                float gg = tanhf(gv[3][hh]);
                float c  = fg * cold[hh] + ig * gg;
                cnew[hh] = c;
                hnew[hh] = og * tanhf(c);
            }
            *(f4*)&Cst[base] = cnew;
        }
        hreg[rr] = hnew;
    }

    __syncthreads();
    #pragma unroll
    for (int hh = 0; hh < 4; ++hh) {
        h4 vh, vl;
        #pragma unroll
        for (int rr = 0; rr < 4; ++rr) {
            float v = hreg[rr][hh];
            _Float16 hi = (_Float16)v;
            vh[rr] = hi;
            vl[rr] = (_Float16)((v - (float)hi) * 2048.f);
        }
        *(h4*)&Sh[tx * 4 + hh][ty * 4] = vh;
        *(h4*)&Sl[tx * 4 + hh][ty * 4] = vl;
    }
    __syncthreads();
    #pragma unroll
    for (int pass = 0; pass < 2; ++pass) {
        const int c = pass * 256 + tid;
        const int row = c >> 3;
        const int off = (c & 7) * 8;
        const size_t go = (size_t)(nbase + b * 64 + row) * 1024 + i0 + off;
        *(h8*)&HTh[go] = *(const h8*)&Sh[row][off];
        *(h8*)&HTl[go] = *(const h8*)&Sl[row][off];
    }
}

// ---------------- final projection from HT rows 4096: (H1^T split f16) ----------------
__global__ __launch_bounds__(256) void proj_f16(const _Float16* __restrict__ HTh,
                                                const _Float16* __restrict__ HTl,
                                                const float* __restrict__ Wpj,
                                                const float* __restrict__ bp,
                                                float* __restrict__ out)
{
    int i = blockIdx.x * 256 + threadIdx.x;
    if (i >= 1000) return;
    int b = blockIdx.y;
    float hv[64];
    #pragma unroll
    for (int h = 0; h < 64; ++h) {
        size_t o = (size_t)(4096 + b * 64 + h) * 1024 + i;
        hv[h] = (float)HTh[o] + (float)HTl[o] * (1.f / 2048.f);
    }
    #pragma unroll
    for (int hor = 0; hor < 12; ++hor) {
        float s = bp[hor];
        #pragma unroll
        for (int h = 0; h < 64; ++h) s = fmaf(hv[h], Wpj[hor * 64 + h], s);
        out[(size_t)(b * 12 + hor) * 1000 + i] = s;
    }
}

extern "C" void kernel_launch(void* const* d_in, const int* in_sizes, int n_in,
                              void* d_out, int out_size, void* d_ws, size_t ws_size,
                              hipStream_t stream)
{
    const float* x   = (const float*)d_in[0];
    const float* E1  = (const float*)d_in[1];
    const float* E2  = (const float*)d_in[2];
    const float* Wx0 = (const float*)d_in[3];
    const float* bx0 = (const float*)d_in[4];
    const float* Wh0 = (const float*)d_in[5];
    const float* bh0 = (const float*)d_in[6];
    const float* Wx1 = (const float*)d_in[7];
    const float* bx1 = (const float*)d_in[8];
    const float* Wh1 = (const float*)d_in[9];
    const float* bh1 = (const float*)d_in[10];
    const float* Wp  = (const float*)d_in[11];
    const float* bp  = (const float*)d_in[12];
    float* out = (float*)d_out;
    float* ws  = (float*)d_ws;

    float*    AX  = ws + WS_AX;
    float*    AHC = ws + WS_AHC;
    float*    C0  = ws + WS_C0;
    float*    C1  = ws + WS_C1;
    _Float16* HTh = (_Float16*)(ws + WS_HTH);
    _Float16* HTl = (_Float16*)(ws + WS_HTL);
    _Float16* Ah  = (_Float16*)(ws + WS_A16H);
    _Float16* Al  = (_Float16*)(ws + WS_A16L);
    float*    W0T = ws + WS_W0T;
    float*    W1T = ws + WS_W1T;
    float*    At  = ws + WS_C0;    // alias: dead before the big zero
    float*    Xr  = ws + WS_AHC;   // alias: dead before the big zero

    compute_A<<<1000, 256, 0, stream>>>(E1, E2, At);
    transpose_x<<<24000, 256, 0, stream>>>(x, Xr);
    gemm1000<<<dim3(16, 48), 256, 0, stream>>>(At, Xr, AX, 6144);   // AX = A @ Xr
    prep_w<<<192, 256, 0, stream>>>(Wh0, Wx1, Wh1, W0T, W1T);
    prep_A<<<4096, 256, 0, stream>>>(At, Ah, Al);
    // single zero over contiguous AHC,C0,C1,HTh,HTl (kills At and Xr aliases)
    zero_kernel<<<24384, 256, 0, stream>>>(AHC, 6242304);

    // prologue: layer0(0) with AHC=0 -> H0(0), C0(0), HT rows 0:4096
    gates_f<<<1024, 256, 0, stream>>>(AHC, 0, W0T, bh0, bx0,
                                      AX, Wx0, 0, C0, HTh, HTl, 0);
    for (int t = 0; t < 48; ++t) {
        // AHC = A @ [H0(t) | H1(t-1)]
        gemm_m<<<1024, 256, 0, stream>>>(Ah, Al, HTh, HTl, AHC);
        // layer1(t) + layer0(t+1) in one grid (independent halves).
        // t=47's layer0 output (H0(48), x index (t+1)&47=0) is never read.
        gates_c<<<2048, 256, 0, stream>>>(AHC, W1T, W0T, bh1, bx1, bh0, bx0,
                                          AX, Wx0, (t + 1) & 47, C1, C0, HTh, HTl);
    }
    proj_f16<<<dim3(4, 64), 256, 0, stream>>>(HTh, HTl, Wp, bp, out);
    (void)in_sizes; (void)n_in; (void)out_size; (void)ws_size;
}

// Round 14
// 7899.342 us; speedup vs baseline: 4.0985x; 1.0177x over previous
//
#include <hip/hip_runtime.h>
#include <math.h>

typedef float f4 __attribute__((ext_vector_type(4)));
typedef _Float16 h4 __attribute__((ext_vector_type(4)));
typedef _Float16 h8 __attribute__((ext_vector_type(8)));

// ---------------- workspace layout (float offsets), total 32,210,944 = 128.84 MB (R10-proven) ----
// AX  : A@x all t [i][t*128+b*2+c]      6,144,000
// AHC : A@[H0|H1] fp32 [1024][8192]     8,388,608
// C0,C1: cell state fp32 [b][1000][64]  2 x 4,096,000
// HTh/l: [H0|H1]^T split f16 [8192][1024]  2 x 4,194,304
// Ah/Al: split f16 A [1024][1024]       2 x 524,288
// W0T [64][256], W1T [128][256] fp32
// pre-zero aliases: At fp32 (1M) in C0; XrTh (3.15M) in C1; XrTl (3.15M) in HTh.
#define WS_AX    0
#define WS_AHC   6144000
#define WS_C0    14532608
#define WS_C1    18628608
#define WS_HTH   22724608
#define WS_HTL   26918912
#define WS_A16H  31113216
#define WS_A16L  31637504
#define WS_W0T   32161792
#define WS_W1T   32178176
// end = 32,210,944

// ---------------- A = softmax(relu(E1 @ E2^T)) in fp64, store A^T ----------------
__global__ __launch_bounds__(256) void compute_A(const float* __restrict__ E1,
                                                 const float* __restrict__ E2,
                                                 float* __restrict__ At)
{
    __shared__ double z[1000];
    __shared__ double red[256];
    __shared__ double e1[16];
    const int i = blockIdx.x;
    const int tid = threadIdx.x;
    if (tid < 16) e1[tid] = (double)E1[i * 16 + tid];
    __syncthreads();
    double lmax = -1e300;
    for (int j = tid; j < 1000; j += 256) {
        double s = 0.0;
        #pragma unroll
        for (int c = 0; c < 16; ++c) s += e1[c] * (double)E2[j * 16 + c];
        if (s < 0.0) s = 0.0;
        z[j] = s;
        if (s > lmax) lmax = s;
    }
    red[tid] = lmax; __syncthreads();
    for (int off = 128; off > 0; off >>= 1) {
        if (tid < off) red[tid] = fmax(red[tid], red[tid + off]);
        __syncthreads();
    }
    const double zmax = red[0];
    __syncthreads();
    double lsum = 0.0;
    for (int j = tid; j < 1000; j += 256) {
        double e = exp(z[j] - zmax);
        z[j] = e;
        lsum += e;
    }
    red[tid] = lsum; __syncthreads();
    for (int off = 128; off > 0; off >>= 1) {
        if (tid < off) red[tid] += red[tid + off];
        __syncthreads();
    }
    const double inv = 1.0 / red[0];
    for (int j = tid; j < 1000; j += 256)
        At[(size_t)j * 1000 + i] = (float)(z[j] * inv);
}

// ---------------- x [B,T,N,C] -> XrT split f16 [n=t*128+b*2+c][j] ----------------
// Block = one (t,b) pair (3072 blocks). float2 read covers c=0,1 -> rows r0, r0+1024.
__global__ __launch_bounds__(256) void transpose_xs(const float* __restrict__ x,
                                                    _Float16* __restrict__ XTh,
                                                    _Float16* __restrict__ XTl)
{
    const int bid = blockIdx.x;
    const int t = bid >> 6, b = bid & 63;
    const int tid = threadIdx.x;
    const size_t xbase = ((size_t)(b * 48 + t)) * 2000;
    const size_t r0 = (size_t)(t * 128 + b * 2) * 1024;
    for (int j = tid; j < 1024; j += 256) {
        float v0 = 0.f, v1 = 0.f;
        if (j < 1000) {
            float2 v = *(const float2*)&x[xbase + (size_t)j * 2];
            v0 = v.x; v1 = v.y;
        }
        _Float16 p0 = (_Float16)v0, p1 = (_Float16)v1;
        XTh[r0 + j]        = p0;
        XTl[r0 + j]        = (_Float16)((v0 - (float)p0) * 2048.f);
        XTh[r0 + 1024 + j] = p1;
        XTl[r0 + 1024 + j] = (_Float16)((v1 - (float)p1) * 2048.f);
    }
}

__global__ __launch_bounds__(256) void zero_kernel(float* __restrict__ p, int n4)
{
    int i = blockIdx.x * 256 + threadIdx.x;
    if (i < n4) { f4 z = {0.f, 0.f, 0.f, 0.f}; ((f4*)p)[i] = z; }
}

// ---------------- weight transposes to [k][256] fp32 (once; R7-proven) ----------------
__global__ __launch_bounds__(256) void prep_w(const float* __restrict__ Wh0,
                                              const float* __restrict__ Wx1,
                                              const float* __restrict__ Wh1,
                                              float* __restrict__ W0T,
                                              float* __restrict__ W1T)
{
    int idx = blockIdx.x * 256 + threadIdx.x;
    if (idx < 16384) {
        int k = idx >> 8, o = idx & 255;
        W0T[idx] = Wh0[o * 64 + k];
    }
    int j = idx - 16384;
    if (j >= 0 && j < 32768) {
        int k = j >> 8, o = j & 255;
        W1T[j] = (k < 64) ? Wx1[o * 64 + k] : Wh1[o * 64 + (k - 64)];
    }
}

// ---------------- split A^T fp32 -> Ah/Al f16 [m=1024][k=1024] ----------------
__global__ __launch_bounds__(256) void prep_A(const float* __restrict__ At,
                                              _Float16* __restrict__ Ahh,
                                              _Float16* __restrict__ All)
{
    int idx = blockIdx.x * 256 + threadIdx.x;   // 1,048,576
    int m = idx >> 10, k = idx & 1023;
    float v = (m < 1000 && k < 1000) ? At[(size_t)k * 1000 + m] : 0.f;
    _Float16 hi = (_Float16)v;
    Ahh[idx] = hi;
    All[idx] = (_Float16)((v - (float)hi) * 2048.f);
}

// ---------------- shared MFMA GEMM machinery (R12-proven body) ----------------
#define GL16(srcp, dstoff) \
    __builtin_amdgcn_global_load_lds((const __attribute__((address_space(1))) unsigned int*)(srcp), \
        (__attribute__((address_space(3))) unsigned int*)(lds + (dstoff)), 16, 0, 0)

__device__ __forceinline__ int swzb(int row, int lg) {
    return row * 64 + ((lg ^ ((row ^ (row >> 2)) & 3)) << 4);
}

// AHC[1024][8192] = A @ HT^T ; XCD-aware n mapping.
__global__ __launch_bounds__(256, 2) void gemm_m(
    const _Float16* __restrict__ Ahg, const _Float16* __restrict__ Alg,
    const _Float16* __restrict__ Bhg, const _Float16* __restrict__ Blg,
    float* __restrict__ Cout)
{
    __shared__ __align__(1024) char lds[24576];
    const int tid = threadIdx.x;
    const int lane = tid & 63;
    const int w = tid >> 6;
    const int lg = lane >> 4, l15 = lane & 15;
    const int xcd = blockIdx.x & 7;
    const int j = blockIdx.x >> 3;
    const int m0 = (j >> 3) * 64;
    const int n0 = (xcd * 8 + (j & 7)) * 128;

    const int r16 = lane >> 2;
    const int sd = lane & 3;
    const char* src[6];
    #pragma unroll
    for (int q = 0; q < 6; ++q) {
        const int c = w * 6 + q;
        int row;
        const _Float16* g;
        if (c < 4)       { row = (c)      * 16 + r16; g = Ahg + (size_t)(m0 + row) * 1024; }
        else if (c < 8)  { row = (c - 4)  * 16 + r16; g = Alg + (size_t)(m0 + row) * 1024; }
        else if (c < 16) { row = (c - 8)  * 16 + r16; g = Bhg + (size_t)(n0 + row) * 1024; }
        else             { row = (c - 16) * 16 + r16; g = Blg + (size_t)(n0 + row) * 1024; }
        const int cg = sd ^ ((row ^ (row >> 2)) & 3);
        src[q] = (const char*)(g + cg * 8);
    }

    f4 acc0[4][2], acc1[4][2];
    #pragma unroll
    for (int a = 0; a < 4; ++a)
        #pragma unroll
        for (int b = 0; b < 2; ++b) {
            acc0[a][b] = (f4){0.f, 0.f, 0.f, 0.f};
            acc1[a][b] = (f4){0.f, 0.f, 0.f, 0.f};
        }

    for (int ks = 0; ks < 32; ++ks) {
        const int kadv = ks * 64;
        #pragma unroll
        for (int q = 0; q < 6; ++q)
            GL16(src[q] + kadv, (w * 6 + q) * 1024);
        __syncthreads();

        h8 fa[4], fl[4], bh[2], bl[2];
        #pragma unroll
        for (int mf = 0; mf < 4; ++mf) {
            const int ob = swzb(mf * 16 + l15, lg);
            fa[mf] = *(const h8*)(lds + ob);
            fl[mf] = *(const h8*)(lds + 4096 + ob);
        }
        #pragma unroll
        for (int nf = 0; nf < 2; ++nf) {
            const int ob = swzb(w * 32 + nf * 16 + l15, lg);
            bh[nf] = *(const h8*)(lds + 8192 + ob);
            bl[nf] = *(const h8*)(lds + 16384 + ob);
        }
        __syncthreads();

        #pragma unroll
        for (int nf = 0; nf < 2; ++nf)
            #pragma unroll
            for (int mf = 0; mf < 4; ++mf) {
                acc0[mf][nf] = __builtin_amdgcn_mfma_f32_16x16x32_f16(fa[mf], bh[nf], acc0[mf][nf], 0, 0, 0);
                acc1[mf][nf] = __builtin_amdgcn_mfma_f32_16x16x32_f16(fa[mf], bl[nf], acc1[mf][nf], 0, 0, 0);
                acc1[mf][nf] = __builtin_amdgcn_mfma_f32_16x16x32_f16(fl[mf], bh[nf], acc1[mf][nf], 0, 0, 0);
            }
    }

    #pragma unroll
    for (int mf = 0; mf < 4; ++mf)
        #pragma unroll
        for (int nf = 0; nf < 2; ++nf) {
            const int row = m0 + mf * 16 + lg * 4;
            const int col = n0 + w * 32 + nf * 16 + l15;
            #pragma unroll
            for (int e = 0; e < 4; ++e)
                Cout[(size_t)(row + e) * 8192 + col] =
                    acc0[mf][nf][e] + acc1[mf][nf][e] * (1.f / 2048.f);
        }
}

// AX[1024][6144] = A @ XrT^T (same body; stride 6144; grid 16 m x 48 n = 768).
// Rows 1000..1023 overflow into the AHC region, which is zeroed immediately after.
__global__ __launch_bounds__(256, 2) void gemm_ax(
    const _Float16* __restrict__ Ahg, const _Float16* __restrict__ Alg,
    const _Float16* __restrict__ Bhg, const _Float16* __restrict__ Blg,
    float* __restrict__ Cout)
{
    __shared__ __align__(1024) char lds[24576];
    const int tid = threadIdx.x;
    const int lane = tid & 63;
    const int w = tid >> 6;
    const int lg = lane >> 4, l15 = lane & 15;
    const int m0 = (blockIdx.x & 15) * 64;
    const int n0 = (blockIdx.x >> 4) * 128;

    const int r16 = lane >> 2;
    const int sd = lane & 3;
    const char* src[6];
    #pragma unroll
    for (int q = 0; q < 6; ++q) {
        const int c = w * 6 + q;
        int row;
        const _Float16* g;
        if (c < 4)       { row = (c)      * 16 + r16; g = Ahg + (size_t)(m0 + row) * 1024; }
        else if (c < 8)  { row = (c - 4)  * 16 + r16; g = Alg + (size_t)(m0 + row) * 1024; }
        else if (c < 16) { row = (c - 8)  * 16 + r16; g = Bhg + (size_t)(n0 + row) * 1024; }
        else             { row = (c - 16) * 16 + r16; g = Blg + (size_t)(n0 + row) * 1024; }
        const int cg = sd ^ ((row ^ (row >> 2)) & 3);
        src[q] = (const char*)(g + cg * 8);
    }

    f4 acc0[4][2], acc1[4][2];
    #pragma unroll
    for (int a = 0; a < 4; ++a)
        #pragma unroll
        for (int b = 0; b < 2; ++b) {
            acc0[a][b] = (f4){0.f, 0.f, 0.f, 0.f};
            acc1[a][b] = (f4){0.f, 0.f, 0.f, 0.f};
        }

    for (int ks = 0; ks < 32; ++ks) {
        const int kadv = ks * 64;
        #pragma unroll
        for (int q = 0; q < 6; ++q)
            GL16(src[q] + kadv, (w * 6 + q) * 1024);
        __syncthreads();

        h8 fa[4], fl[4], bh[2], bl[2];
        #pragma unroll
        for (int mf = 0; mf < 4; ++mf) {
            const int ob = swzb(mf * 16 + l15, lg);
            fa[mf] = *(const h8*)(lds + ob);
            fl[mf] = *(const h8*)(lds + 4096 + ob);
        }
        #pragma unroll
        for (int nf = 0; nf < 2; ++nf) {
            const int ob = swzb(w * 32 + nf * 16 + l15, lg);
            bh[nf] = *(const h8*)(lds + 8192 + ob);
            bl[nf] = *(const h8*)(lds + 16384 + ob);
        }
        __syncthreads();

        #pragma unroll
        for (int nf = 0; nf < 2; ++nf)
            #pragma unroll
            for (int mf = 0; mf < 4; ++mf) {
                acc0[mf][nf] = __builtin_amdgcn_mfma_f32_16x16x32_f16(fa[mf], bh[nf], acc0[mf][nf], 0, 0, 0);
                acc1[mf][nf] = __builtin_amdgcn_mfma_f32_16x16x32_f16(fa[mf], bl[nf], acc1[mf][nf], 0, 0, 0);
                acc1[mf][nf] = __builtin_amdgcn_mfma_f32_16x16x32_f16(fl[mf], bh[nf], acc1[mf][nf], 0, 0, 0);
            }
    }

    #pragma unroll
    for (int mf = 0; mf < 4; ++mf)
        #pragma unroll
        for (int nf = 0; nf < 2; ++nf) {
            const int row = m0 + mf * 16 + lg * 4;
            const int col = n0 + w * 32 + nf * 16 + l15;
            #pragma unroll
            for (int e = 0; e < 4; ++e)
                Cout[(size_t)(row + e) * 6144 + col] =
                    acc0[mf][nf][e] + acc1[mf][nf][e] * (1.f / 2048.f);
        }
}

// ---------------- combined gates (R13-proven, unchanged) ----------------
__global__ __launch_bounds__(256) void gates_c(
    const float* __restrict__ AHC,
    const float* __restrict__ W1T, const float* __restrict__ W0T,
    const float* __restrict__ bh1, const float* __restrict__ bx1,
    const float* __restrict__ bh0, const float* __restrict__ bx0,
    const float* __restrict__ AX, const float* __restrict__ Wx0E, int tnext,
    float* __restrict__ C1, float* __restrict__ C0,
    _Float16* __restrict__ HTh, _Float16* __restrict__ HTl)
{
    __shared__ __align__(16) char smem[43520];
    float (*As)[68] = (float(*)[68])smem;
    float *Bs       = (float*)(smem + 8704);
    float *wx       = (float*)(smem + 41472);
    _Float16 (*Sh)[80] = (_Float16(*)[80])smem;
    _Float16 (*Sl)[80] = (_Float16(*)[80])(smem + 10240);

    const int half = blockIdx.x >> 10;
    const int bidx = blockIdx.x & 1023;
    const int two  = half ^ 1;
    const float* WT  = half ? W0T : W1T;
    const float* b1  = half ? bh0 : bh1;
    const float* b2  = half ? bx0 : bx1;
    const float* WxE = half ? Wx0E : nullptr;
    float* Cst = half ? C0 : C1;
    const int nbase = half ? 0 : 4096;
    const int t = tnext;

    const int tid = threadIdx.x;
    const int tx = tid & 15;
    const int ty = tid >> 4;
    const int i0 = (bidx >> 6) * 64;
    const int b  = bidx & 63;
    const int mrow = tid >> 3;
    const int f4i  = tid & 7;

    if (WxE && tid < 128) ((f4*)wx)[tid] = ((const f4*)WxE)[tid];

    f4 acc[4][4];
    #pragma unroll
    for (int r = 0; r < 4; ++r)
        #pragma unroll
        for (int gq = 0; gq < 4; ++gq) acc[r][gq] = (f4){0.f, 0.f, 0.f, 0.f};

    const int nchunk = two ? 4 : 2;
    for (int ch = 0; ch < nchunk; ++ch) {
        const int coff = ((ch < 2) ? 0 : 4096) + b * 64;
        const int koff = (ch & 1) * 32;
        f4 av0 = *(const f4*)&AHC[(size_t)(i0 + mrow) * 8192 + coff + koff + f4i * 4];
        f4 av1 = *(const f4*)&AHC[(size_t)(i0 + mrow + 32) * 8192 + coff + koff + f4i * 4];
        const float* wsrc = WT + ch * 8192;
        f4 bv[8];
        #pragma unroll
        for (int r = 0; r < 8; ++r) bv[r] = *(const f4*)&wsrc[(tid + r * 256) * 4];
        __syncthreads();
        #pragma unroll
        for (int j = 0; j < 4; ++j) {
            As[f4i * 4 + j][mrow]      = av0[j];
            As[f4i * 4 + j][mrow + 32] = av1[j];
        }
        #pragma unroll
        for (int r = 0; r < 8; ++r) *(f4*)&Bs[(tid + r * 256) * 4] = bv[r];
        __syncthreads();
        #pragma unroll
        for (int k = 0; k < 32; ++k) {
            f4 av = *(const f4*)&As[k][ty * 4];
            f4 bq[4];
            #pragma unroll
            for (int gq = 0; gq < 4; ++gq) bq[gq] = *(const f4*)&Bs[k * 256 + gq * 64 + tx * 4];
            #pragma unroll
            for (int rr = 0; rr < 4; ++rr)
                #pragma unroll
                for (int gq = 0; gq < 4; ++gq)
                    acc[rr][gq] += av[rr] * bq[gq];
        }
    }

    f4 bb[4];
    #pragma unroll
    for (int gq = 0; gq < 4; ++gq) {
        f4 v1 = *(const f4*)&b1[gq * 64 + tx * 4];
        f4 v2 = *(const f4*)&b2[gq * 64 + tx * 4];
        bb[gq] = v1 + v2;
    }

    f4 hreg[4];
    #pragma unroll
    for (int rr = 0; rr < 4; ++rr) {
        const int i = i0 + ty * 4 + rr;
        const bool valid = (i < 1000);
        f4 gv[4];
        #pragma unroll
        for (int gq = 0; gq < 4; ++gq) gv[gq] = acc[rr][gq] + bb[gq];
        if (WxE && valid) {
            float x0 = AX[(size_t)i * 6144 + t * 128 + b * 2 + 0];
            float x1 = AX[(size_t)i * 6144 + t * 128 + b * 2 + 1];
            #pragma unroll
            for (int gq = 0; gq < 4; ++gq)
                #pragma unroll
                for (int hh = 0; hh < 4; ++hh) {
                    int gc = gq * 64 + tx * 4 + hh;
                    gv[gq][hh] = fmaf(x0, wx[gc * 2 + 0],
                                 fmaf(x1, wx[gc * 2 + 1], gv[gq][hh]));
                }
        }
        f4 hnew = {0.f, 0.f, 0.f, 0.f};
        if (valid) {
            const size_t base = ((size_t)b * 1000 + i) * 64 + tx * 4;
            f4 cold = *(const f4*)&Cst[base];
            f4 cnew;
            #pragma unroll
            for (int hh = 0; hh < 4; ++hh) {
                float ig = 1.f / (1.f + expf(-gv[0][hh]));
                float fg = 1.f / (1.f + expf(-gv[1][hh]));
                float og = 1.f / (1.f + expf(-gv[2][hh]));
                float gg = tanhf(gv[3][hh]);
                float c  = fg * cold[hh] + ig * gg;
                cnew[hh] = c;
                hnew[hh] = og * tanhf(c);
            }
            *(f4*)&Cst[base] = cnew;
        }
        hreg[rr] = hnew;
    }

    __syncthreads();
    #pragma unroll
    for (int hh = 0; hh < 4; ++hh) {
        h4 vh, vl;
        #pragma unroll
        for (int rr = 0; rr < 4; ++rr) {
            float v = hreg[rr][hh];
            _Float16 hi = (_Float16)v;
            vh[rr] = hi;
            vl[rr] = (_Float16)((v - (float)hi) * 2048.f);
        }
        *(h4*)&Sh[tx * 4 + hh][ty * 4] = vh;
        *(h4*)&Sl[tx * 4 + hh][ty * 4] = vl;
    }
    __syncthreads();
    #pragma unroll
    for (int pass = 0; pass < 2; ++pass) {
        const int c = pass * 256 + tid;
        const int row = c >> 3;
        const int off = (c & 7) * 8;
        const size_t go = (size_t)(nbase + b * 64 + row) * 1024 + i0 + off;
        *(h8*)&HTh[go] = *(const h8*)&Sh[row][off];
        *(h8*)&HTl[go] = *(const h8*)&Sl[row][off];
    }
}

// ---------------- prologue gates (R12-proven, unchanged) ----------------
__global__ __launch_bounds__(256) void gates_f(
    const float* __restrict__ AHC, int two,
    const float* __restrict__ WT,
    const float* __restrict__ b1, const float* __restrict__ b2,
    const float* __restrict__ AX, const float* __restrict__ WxE, int t,
    float* __restrict__ Cst,
    _Float16* __restrict__ HTh, _Float16* __restrict__ HTl, int nbase)
{
    __shared__ __align__(16) char smem[43520];
    float (*As)[68] = (float(*)[68])smem;
    float *Bs       = (float*)(smem + 8704);
    float *wx       = (float*)(smem + 41472);
    _Float16 (*Sh)[80] = (_Float16(*)[80])smem;
    _Float16 (*Sl)[80] = (_Float16(*)[80])(smem + 10240);
    const int tid = threadIdx.x;
    const int tx = tid & 15;
    const int ty = tid >> 4;
    const int i0 = (blockIdx.x >> 6) * 64;
    const int b  = blockIdx.x & 63;
    const int mrow = tid >> 3;
    const int f4i  = tid & 7;

    if (WxE && tid < 128) ((f4*)wx)[tid] = ((const f4*)WxE)[tid];

    f4 acc[4][4];
    #pragma unroll
    for (int r = 0; r < 4; ++r)
        #pragma unroll
        for (int gq = 0; gq < 4; ++gq) acc[r][gq] = (f4){0.f, 0.f, 0.f, 0.f};

    const int nchunk = two ? 4 : 2;
    for (int ch = 0; ch < nchunk; ++ch) {
        const int coff = ((ch < 2) ? 0 : 4096) + b * 64;
        const int koff = (ch & 1) * 32;
        f4 av0 = *(const f4*)&AHC[(size_t)(i0 + mrow) * 8192 + coff + koff + f4i * 4];
        f4 av1 = *(const f4*)&AHC[(size_t)(i0 + mrow + 32) * 8192 + coff + koff + f4i * 4];
        const float* wsrc = WT + ch * 8192;
        f4 bv[8];
        #pragma unroll
        for (int r = 0; r < 8; ++r) bv[r] = *(const f4*)&wsrc[(tid + r * 256) * 4];
        __syncthreads();
        #pragma unroll
        for (int j = 0; j < 4; ++j) {
            As[f4i * 4 + j][mrow]      = av0[j];
            As[f4i * 4 + j][mrow + 32] = av1[j];
        }
        #pragma unroll
        for (int r = 0; r < 8; ++r) *(f4*)&Bs[(tid + r * 256) * 4] = bv[r];
        __syncthreads();
        #pragma unroll
        for (int k = 0; k < 32; ++k) {
            f4 av = *(const f4*)&As[k][ty * 4];
            f4 bq[4];
            #pragma unroll
            for (int gq = 0; gq < 4; ++gq) bq[gq] = *(const f4*)&Bs[k * 256 + gq * 64 + tx * 4];
            #pragma unroll
            for (int rr = 0; rr < 4; ++rr)
                #pragma unroll
                for (int gq = 0; gq < 4; ++gq)
                    acc[rr][gq] += av[rr] * bq[gq];
        }
    }

    f4 bb[4];
    #pragma unroll
    for (int gq = 0; gq < 4; ++gq) {
        f4 v1 = *(const f4*)&b1[gq * 64 + tx * 4];
        f4 v2 = *(const f4*)&b2[gq * 64 + tx * 4];
        bb[gq] = v1 + v2;
    }

    f4 hreg[4];
    #pragma unroll
    for (int rr = 0; rr < 4; ++rr) {
        const int i = i0 + ty * 4 + rr;
        const bool valid = (i < 1000);
        f4 gv[4];
        #pragma unroll
        for (int gq = 0; gq < 4; ++gq) gv[gq] = acc[rr][gq] + bb[gq];
        if (WxE && valid) {
            float x0 = AX[(size_t)i * 6144 + t * 128 + b * 2 + 0];
            float x1 = AX[(size_t)i * 6144 + t * 128 + b * 2 + 1];
            #pragma unroll
            for (int gq = 0; gq < 4; ++gq)
                #pragma unroll
                for (int hh = 0; hh < 4; ++hh) {
                    int gc = gq * 64 + tx * 4 + hh;
                    gv[gq][hh] = fmaf(x0, wx[gc * 2 + 0],
                                 fmaf(x1, wx[gc * 2 + 1], gv[gq][hh]));
                }
        }
        f4 hnew = {0.f, 0.f, 0.f, 0.f};
        if (valid) {
            const size_t base = ((size_t)b * 1000 + i) * 64 + tx * 4;
            f4 cold = *(const f4*)&Cst[base];
            f4 cnew;
            #pragma unroll
            for (int hh = 0; hh < 4; ++hh) {
                float ig = 1.f / (1.f + expf(-gv[0][hh]));
                float fg = 1.f / (1.f + expf(-gv[1][hh]));
                float og = 1.f / (1.f + expf(-gv[2][hh]));
                float gg = tanhf(gv[3][hh]);
                float c  = fg * cold[hh] + ig * gg;
                cnew[hh] = c;
                hnew[hh] = og * tanhf(c);
            }
            *(f4*)&Cst[base] = cnew;
        }
        hreg[rr] = hnew;
    }

    __syncthreads();
    #pragma unroll
    for (int hh = 0; hh < 4; ++hh) {
        h4 vh, vl;
        #pragma unroll
        for (int rr = 0; rr < 4; ++rr) {
            float v = hreg[rr][hh];
            _Float16 hi = (_Float16)v;
            vh[rr] = hi;
            vl[rr] = (_Float16)((v - (float)hi) * 2048.f);
        }
        *(h4*)&Sh[tx * 4 + hh][ty * 4] = vh;
        *(h4*)&Sl[tx * 4 + hh][ty * 4] = vl;
    }
    __syncthreads();
    #pragma unroll
    for (int pass = 0; pass < 2; ++pass) {
        const int c = pass * 256 + tid;
        const int row = c >> 3;
        const int off = (c & 7) * 8;
        const size_t go = (size_t)(nbase + b * 64 + row) * 1024 + i0 + off;
        *(h8*)&HTh[go] = *(const h8*)&Sh[row][off];
        *(h8*)&HTl[go] = *(const h8*)&Sl[row][off];
    }
}

// ---------------- final projection from HT rows 4096: (H1^T split f16) ----------------
__global__ __launch_bounds__(256) void proj_f16(const _Float16* __restrict__ HTh,
                                                const _Float16* __restrict__ HTl,
                                                const float* __restrict__ Wpj,
                                                const float* __restrict__ bp,
                                                float* __restrict__ out)
{
    int i = blockIdx.x * 256 + threadIdx.x;
    if (i >= 1000) return;
    int b = blockIdx.y;
    float hv[64];
    #pragma unroll
    for (int h = 0; h < 64; ++h) {
        size_t o = (size_t)(4096 + b * 64 + h) * 1024 + i;
        hv[h] = (float)HTh[o] + (float)HTl[o] * (1.f / 2048.f);
    }
    #pragma unroll
    for (int hor = 0; hor < 12; ++hor) {
        float s = bp[hor];
        #pragma unroll
        for (int h = 0; h < 64; ++h) s = fmaf(hv[h], Wpj[hor * 64 + h], s);
        out[(size_t)(b * 12 + hor) * 1000 + i] = s;
    }
}

extern "C" void kernel_launch(void* const* d_in, const int* in_sizes, int n_in,
                              void* d_out, int out_size, void* d_ws, size_t ws_size,
                              hipStream_t stream)
{
    const float* x   = (const float*)d_in[0];
    const float* E1  = (const float*)d_in[1];
    const float* E2  = (const float*)d_in[2];
    const float* Wx0 = (const float*)d_in[3];
    const float* bx0 = (const float*)d_in[4];
    const float* Wh0 = (const float*)d_in[5];
    const float* bh0 = (const float*)d_in[6];
    const float* Wx1 = (const float*)d_in[7];
    const float* bx1 = (const float*)d_in[8];
    const float* Wh1 = (const float*)d_in[9];
    const float* bh1 = (const float*)d_in[10];
    const float* Wp  = (const float*)d_in[11];
    const float* bp  = (const float*)d_in[12];
    float* out = (float*)d_out;
    float* ws  = (float*)d_ws;

    float*    AX  = ws + WS_AX;
    float*    AHC = ws + WS_AHC;
    float*    C0  = ws + WS_C0;
    float*    C1  = ws + WS_C1;
    _Float16* HTh = (_Float16*)(ws + WS_HTH);
    _Float16* HTl = (_Float16*)(ws + WS_HTL);
    _Float16* Ah  = (_Float16*)(ws + WS_A16H);
    _Float16* Al  = (_Float16*)(ws + WS_A16L);
    float*    W0T = ws + WS_W0T;
    float*    W1T = ws + WS_W1T;
    float*    At  = ws + WS_C0;              // alias: dead before the big zero
    _Float16* XTh = (_Float16*)(ws + WS_C1); // alias: 3,145,728 f32-slots, dead before zero
    _Float16* XTl = (_Float16*)(ws + WS_HTH);// alias: dead before zero

    compute_A<<<1000, 256, 0, stream>>>(E1, E2, At);
    transpose_xs<<<3072, 256, 0, stream>>>(x, XTh, XTl);
    prep_A<<<4096, 256, 0, stream>>>(At, Ah, Al);
    // AX = A @ x (MFMA split-f16; rows 1000..1023 spill into AHC, zeroed below)
    gemm_ax<<<768, 256, 0, stream>>>(Ah, Al, XTh, XTl, AX);
    prep_w<<<192, 256, 0, stream>>>(Wh0, Wx1, Wh1, W0T, W1T);
    // single zero over contiguous AHC,C0,C1,HTh,HTl (kills At/XTh/XTl aliases + gemm_ax spill)
    zero_kernel<<<24384, 256, 0, stream>>>(AHC, 6242304);

    // prologue: layer0(0) with AHC=0 -> H0(0), C0(0), HT rows 0:4096
    gates_f<<<1024, 256, 0, stream>>>(AHC, 0, W0T, bh0, bx0,
                                      AX, Wx0, 0, C0, HTh, HTl, 0);
    for (int t = 0; t < 48; ++t) {
        // AHC = A @ [H0(t) | H1(t-1)]
        gemm_m<<<1024, 256, 0, stream>>>(Ah, Al, HTh, HTl, AHC);
        // layer1(t) + layer0(t+1) in one grid (independent halves)
        gates_c<<<2048, 256, 0, stream>>>(AHC, W1T, W0T, bh1, bx1, bh0, bx0,
                                          AX, Wx0, (t + 1) & 47, C1, C0, HTh, HTl);
    }
    proj_f16<<<dim3(4, 64), 256, 0, stream>>>(HTh, HTl, Wp, bp, out);
    (void)in_sizes; (void)n_in; (void)out_size; (void)ws_size;
}

// Round 15
// 7682.512 us; speedup vs baseline: 4.2142x; 1.0282x over previous
//
#include <hip/hip_runtime.h>
#include <math.h>

typedef float f4 __attribute__((ext_vector_type(4)));
typedef _Float16 h4 __attribute__((ext_vector_type(4)));
typedef _Float16 h8 __attribute__((ext_vector_type(8)));

// ---------------- workspace layout (float offsets), total 32,210,944 = 128.84 MB (R10-proven) ----
#define WS_AX    0
#define WS_AHC   6144000
#define WS_C0    14532608
#define WS_C1    18628608
#define WS_HTH   22724608
#define WS_HTL   26918912
#define WS_A16H  31113216
#define WS_A16L  31637504
#define WS_W0T   32161792
#define WS_W1T   32178176
// end = 32,210,944

// ---------------- A = softmax(relu(E1 @ E2^T)) in fp64, store A^T ----------------
__global__ __launch_bounds__(256) void compute_A(const float* __restrict__ E1,
                                                 const float* __restrict__ E2,
                                                 float* __restrict__ At)
{
    __shared__ double z[1000];
    __shared__ double red[256];
    __shared__ double e1[16];
    const int i = blockIdx.x;
    const int tid = threadIdx.x;
    if (tid < 16) e1[tid] = (double)E1[i * 16 + tid];
    __syncthreads();
    double lmax = -1e300;
    for (int j = tid; j < 1000; j += 256) {
        double s = 0.0;
        #pragma unroll
        for (int c = 0; c < 16; ++c) s += e1[c] * (double)E2[j * 16 + c];
        if (s < 0.0) s = 0.0;
        z[j] = s;
        if (s > lmax) lmax = s;
    }
    red[tid] = lmax; __syncthreads();
    for (int off = 128; off > 0; off >>= 1) {
        if (tid < off) red[tid] = fmax(red[tid], red[tid + off]);
        __syncthreads();
    }
    const double zmax = red[0];
    __syncthreads();
    double lsum = 0.0;
    for (int j = tid; j < 1000; j += 256) {
        double e = exp(z[j] - zmax);
        z[j] = e;
        lsum += e;
    }
    red[tid] = lsum; __syncthreads();
    for (int off = 128; off > 0; off >>= 1) {
        if (tid < off) red[tid] += red[tid + off];
        __syncthreads();
    }
    const double inv = 1.0 / red[0];
    for (int j = tid; j < 1000; j += 256)
        At[(size_t)j * 1000 + i] = (float)(z[j] * inv);
}

// ---------------- x [B,T,N,C] -> XrT split f16 [n=t*128+b*2+c][j] ----------------
__global__ __launch_bounds__(256) void transpose_xs(const float* __restrict__ x,
                                                    _Float16* __restrict__ XTh,
                                                    _Float16* __restrict__ XTl)
{
    const int bid = blockIdx.x;
    const int t = bid >> 6, b = bid & 63;
    const int tid = threadIdx.x;
    const size_t xbase = ((size_t)(b * 48 + t)) * 2000;
    const size_t r0 = (size_t)(t * 128 + b * 2) * 1024;
    for (int j = tid; j < 1024; j += 256) {
        float v0 = 0.f, v1 = 0.f;
        if (j < 1000) {
            float2 v = *(const float2*)&x[xbase + (size_t)j * 2];
            v0 = v.x; v1 = v.y;
        }
        _Float16 p0 = (_Float16)v0, p1 = (_Float16)v1;
        XTh[r0 + j]        = p0;
        XTl[r0 + j]        = (_Float16)((v0 - (float)p0) * 2048.f);
        XTh[r0 + 1024 + j] = p1;
        XTl[r0 + 1024 + j] = (_Float16)((v1 - (float)p1) * 2048.f);
    }
}

__global__ __launch_bounds__(256) void zero_kernel(float* __restrict__ p, int n4)
{
    int i = blockIdx.x * 256 + threadIdx.x;
    if (i < n4) { f4 z = {0.f, 0.f, 0.f, 0.f}; ((f4*)p)[i] = z; }
}

// ---------------- weight transposes to [k][256] fp32 (once; R7-proven) ----------------
__global__ __launch_bounds__(256) void prep_w(const float* __restrict__ Wh0,
                                              const float* __restrict__ Wx1,
                                              const float* __restrict__ Wh1,
                                              float* __restrict__ W0T,
                                              float* __restrict__ W1T)
{
    int idx = blockIdx.x * 256 + threadIdx.x;
    if (idx < 16384) {
        int k = idx >> 8, o = idx & 255;
        W0T[idx] = Wh0[o * 64 + k];
    }
    int j = idx - 16384;
    if (j >= 0 && j < 32768) {
        int k = j >> 8, o = j & 255;
        W1T[j] = (k < 64) ? Wx1[o * 64 + k] : Wh1[o * 64 + (k - 64)];
    }
}

// ---------------- split A^T fp32 -> Ah/Al f16 [m=1024][k=1024] ----------------
__global__ __launch_bounds__(256) void prep_A(const float* __restrict__ At,
                                              _Float16* __restrict__ Ahh,
                                              _Float16* __restrict__ All)
{
    int idx = blockIdx.x * 256 + threadIdx.x;   // 1,048,576
    int m = idx >> 10, k = idx & 1023;
    float v = (m < 1000 && k < 1000) ? At[(size_t)k * 1000 + m] : 0.f;
    _Float16 hi = (_Float16)v;
    Ahh[idx] = hi;
    All[idx] = (_Float16)((v - (float)hi) * 2048.f);
}

// ---------------- shared MFMA GEMM machinery (R12-proven body) ----------------
#define GL16(srcp, dstoff) \
    __builtin_amdgcn_global_load_lds((const __attribute__((address_space(1))) unsigned int*)(srcp), \
        (__attribute__((address_space(3))) unsigned int*)(lds + (dstoff)), 16, 0, 0)

__device__ __forceinline__ int swzb(int row, int lg) {
    return row * 64 + ((lg ^ ((row ^ (row >> 2)) & 3)) << 4);
}

// AHC[1024][8192] = A @ HT^T ; XCD-aware n mapping.
__global__ __launch_bounds__(256, 2) void gemm_m(
    const _Float16* __restrict__ Ahg, const _Float16* __restrict__ Alg,
    const _Float16* __restrict__ Bhg, const _Float16* __restrict__ Blg,
    float* __restrict__ Cout)
{
    __shared__ __align__(1024) char lds[24576];
    const int tid = threadIdx.x;
    const int lane = tid & 63;
    const int w = tid >> 6;
    const int lg = lane >> 4, l15 = lane & 15;
    const int xcd = blockIdx.x & 7;
    const int j = blockIdx.x >> 3;
    const int m0 = (j >> 3) * 64;
    const int n0 = (xcd * 8 + (j & 7)) * 128;

    const int r16 = lane >> 2;
    const int sd = lane & 3;
    const char* src[6];
    #pragma unroll
    for (int q = 0; q < 6; ++q) {
        const int c = w * 6 + q;
        int row;
        const _Float16* g;
        if (c < 4)       { row = (c)      * 16 + r16; g = Ahg + (size_t)(m0 + row) * 1024; }
        else if (c < 8)  { row = (c - 4)  * 16 + r16; g = Alg + (size_t)(m0 + row) * 1024; }
        else if (c < 16) { row = (c - 8)  * 16 + r16; g = Bhg + (size_t)(n0 + row) * 1024; }
        else             { row = (c - 16) * 16 + r16; g = Blg + (size_t)(n0 + row) * 1024; }
        const int cg = sd ^ ((row ^ (row >> 2)) & 3);
        src[q] = (const char*)(g + cg * 8);
    }

    f4 acc0[4][2], acc1[4][2];
    #pragma unroll
    for (int a = 0; a < 4; ++a)
        #pragma unroll
        for (int b = 0; b < 2; ++b) {
            acc0[a][b] = (f4){0.f, 0.f, 0.f, 0.f};
            acc1[a][b] = (f4){0.f, 0.f, 0.f, 0.f};
        }

    for (int ks = 0; ks < 32; ++ks) {
        const int kadv = ks * 64;
        #pragma unroll
        for (int q = 0; q < 6; ++q)
            GL16(src[q] + kadv, (w * 6 + q) * 1024);
        __syncthreads();

        h8 fa[4], fl[4], bh[2], bl[2];
        #pragma unroll
        for (int mf = 0; mf < 4; ++mf) {
            const int ob = swzb(mf * 16 + l15, lg);
            fa[mf] = *(const h8*)(lds + ob);
            fl[mf] = *(const h8*)(lds + 4096 + ob);
        }
        #pragma unroll
        for (int nf = 0; nf < 2; ++nf) {
            const int ob = swzb(w * 32 + nf * 16 + l15, lg);
            bh[nf] = *(const h8*)(lds + 8192 + ob);
            bl[nf] = *(const h8*)(lds + 16384 + ob);
        }
        __syncthreads();

        #pragma unroll
        for (int nf = 0; nf < 2; ++nf)
            #pragma unroll
            for (int mf = 0; mf < 4; ++mf) {
                acc0[mf][nf] = __builtin_amdgcn_mfma_f32_16x16x32_f16(fa[mf], bh[nf], acc0[mf][nf], 0, 0, 0);
                acc1[mf][nf] = __builtin_amdgcn_mfma_f32_16x16x32_f16(fa[mf], bl[nf], acc1[mf][nf], 0, 0, 0);
                acc1[mf][nf] = __builtin_amdgcn_mfma_f32_16x16x32_f16(fl[mf], bh[nf], acc1[mf][nf], 0, 0, 0);
            }
    }

    #pragma unroll
    for (int mf = 0; mf < 4; ++mf)
        #pragma unroll
        for (int nf = 0; nf < 2; ++nf) {
            const int row = m0 + mf * 16 + lg * 4;
            const int col = n0 + w * 32 + nf * 16 + l15;
            #pragma unroll
            for (int e = 0; e < 4; ++e)
                Cout[(size_t)(row + e) * 8192 + col] =
                    acc0[mf][nf][e] + acc1[mf][nf][e] * (1.f / 2048.f);
        }
}

// AX[1024][6144] = A @ XrT^T (same body; stride 6144; grid 768).
__global__ __launch_bounds__(256, 2) void gemm_ax(
    const _Float16* __restrict__ Ahg, const _Float16* __restrict__ Alg,
    const _Float16* __restrict__ Bhg, const _Float16* __restrict__ Blg,
    float* __restrict__ Cout)
{
    __shared__ __align__(1024) char lds[24576];
    const int tid = threadIdx.x;
    const int lane = tid & 63;
    const int w = tid >> 6;
    const int lg = lane >> 4, l15 = lane & 15;
    const int m0 = (blockIdx.x & 15) * 64;
    const int n0 = (blockIdx.x >> 4) * 128;

    const int r16 = lane >> 2;
    const int sd = lane & 3;
    const char* src[6];
    #pragma unroll
    for (int q = 0; q < 6; ++q) {
        const int c = w * 6 + q;
        int row;
        const _Float16* g;
        if (c < 4)       { row = (c)      * 16 + r16; g = Ahg + (size_t)(m0 + row) * 1024; }
        else if (c < 8)  { row = (c - 4)  * 16 + r16; g = Alg + (size_t)(m0 + row) * 1024; }
        else if (c < 16) { row = (c - 8)  * 16 + r16; g = Bhg + (size_t)(n0 + row) * 1024; }
        else             { row = (c - 16) * 16 + r16; g = Blg + (size_t)(n0 + row) * 1024; }
        const int cg = sd ^ ((row ^ (row >> 2)) & 3);
        src[q] = (const char*)(g + cg * 8);
    }

    f4 acc0[4][2], acc1[4][2];
    #pragma unroll
    for (int a = 0; a < 4; ++a)
        #pragma unroll
        for (int b = 0; b < 2; ++b) {
            acc0[a][b] = (f4){0.f, 0.f, 0.f, 0.f};
            acc1[a][b] = (f4){0.f, 0.f, 0.f, 0.f};
        }

    for (int ks = 0; ks < 32; ++ks) {
        const int kadv = ks * 64;
        #pragma unroll
        for (int q = 0; q < 6; ++q)
            GL16(src[q] + kadv, (w * 6 + q) * 1024);
        __syncthreads();

        h8 fa[4], fl[4], bh[2], bl[2];
        #pragma unroll
        for (int mf = 0; mf < 4; ++mf) {
            const int ob = swzb(mf * 16 + l15, lg);
            fa[mf] = *(const h8*)(lds + ob);
            fl[mf] = *(const h8*)(lds + 4096 + ob);
        }
        #pragma unroll
        for (int nf = 0; nf < 2; ++nf) {
            const int ob = swzb(w * 32 + nf * 16 + l15, lg);
            bh[nf] = *(const h8*)(lds + 8192 + ob);
            bl[nf] = *(const h8*)(lds + 16384 + ob);
        }
        __syncthreads();

        #pragma unroll
        for (int nf = 0; nf < 2; ++nf)
            #pragma unroll
            for (int mf = 0; mf < 4; ++mf) {
                acc0[mf][nf] = __builtin_amdgcn_mfma_f32_16x16x32_f16(fa[mf], bh[nf], acc0[mf][nf], 0, 0, 0);
                acc1[mf][nf] = __builtin_amdgcn_mfma_f32_16x16x32_f16(fa[mf], bl[nf], acc1[mf][nf], 0, 0, 0);
                acc1[mf][nf] = __builtin_amdgcn_mfma_f32_16x16x32_f16(fl[mf], bh[nf], acc1[mf][nf], 0, 0, 0);
            }
    }

    #pragma unroll
    for (int mf = 0; mf < 4; ++mf)
        #pragma unroll
        for (int nf = 0; nf < 2; ++nf) {
            const int row = m0 + mf * 16 + lg * 4;
            const int col = n0 + w * 32 + nf * 16 + l15;
            #pragma unroll
            for (int e = 0; e < 4; ++e)
                Cout[(size_t)(row + e) * 6144 + col] =
                    acc0[mf][nf][e] + acc1[mf][nf][e] * (1.f / 2048.f);
        }
}

// ---------------- combined gates v2: 27.1 KB LDS (16-k Bs halves) for 5 blocks/CU ----------------
// Grid 2048: blocks 0..1023 = layer1(t); 1024..2047 = layer0(t+1). Same math as R13/R14.
// LDS: As[32][68] @0 (8704) | Bs[16][256] @8704 (16384) | wx @25088 (2048) = 27136 B.
// Sh/Sl overlay (20480 B) on As+Bs region after compute.
__global__ __launch_bounds__(256) void gates_c(
    const float* __restrict__ AHC,
    const float* __restrict__ W1T, const float* __restrict__ W0T,
    const float* __restrict__ bh1, const float* __restrict__ bx1,
    const float* __restrict__ bh0, const float* __restrict__ bx0,
    const float* __restrict__ AX, const float* __restrict__ Wx0E, int tnext,
    float* __restrict__ C1, float* __restrict__ C0,
    _Float16* __restrict__ HTh, _Float16* __restrict__ HTl)
{
    __shared__ __align__(16) char smem[27136];
    float (*As)[68] = (float(*)[68])smem;                 // 8,704 B
    float *Bs       = (float*)(smem + 8704);              // 16,384 B (16 k-rows)
    float *wx       = (float*)(smem + 25088);             // 2,048 B
    _Float16 (*Sh)[80] = (_Float16(*)[80])smem;           // overlay
    _Float16 (*Sl)[80] = (_Float16(*)[80])(smem + 10240); // overlay, ends 20,480

    const int half = blockIdx.x >> 10;
    const int bidx = blockIdx.x & 1023;
    const int two  = half ^ 1;
    const float* WT  = half ? W0T : W1T;
    const float* b1  = half ? bh0 : bh1;
    const float* b2  = half ? bx0 : bx1;
    const float* WxE = half ? Wx0E : nullptr;
    float* Cst = half ? C0 : C1;
    const int nbase = half ? 0 : 4096;
    const int t = tnext;

    const int tid = threadIdx.x;
    const int tx = tid & 15;
    const int ty = tid >> 4;
    const int i0 = (bidx >> 6) * 64;
    const int b  = bidx & 63;
    const int mrow = tid >> 3;          // 0..31
    const int f4i  = tid & 7;
    const int wrow = tid >> 6;          // 0..3 (W staging base row)
    const int wcol = (tid & 63) * 4;    // W staging col

    if (WxE && tid < 128) ((f4*)wx)[tid] = ((const f4*)WxE)[tid];

    f4 acc[4][4];
    #pragma unroll
    for (int r = 0; r < 4; ++r)
        #pragma unroll
        for (int gq = 0; gq < 4; ++gq) acc[r][gq] = (f4){0.f, 0.f, 0.f, 0.f};

    const int nchunk = two ? 4 : 2;
    for (int ch = 0; ch < nchunk; ++ch) {
        const int coff = ((ch < 2) ? 0 : 4096) + b * 64;
        const int koff = (ch & 1) * 32;
        // reg prefetch (same global traffic as R14)
        f4 av0 = *(const f4*)&AHC[(size_t)(i0 + mrow) * 8192 + coff + koff + f4i * 4];
        f4 av1 = *(const f4*)&AHC[(size_t)(i0 + mrow + 32) * 8192 + coff + koff + f4i * 4];
        const float* wsrc = WT + ch * 8192;
        f4 bv[8];
        #pragma unroll
        for (int r = 0; r < 8; ++r) bv[r] = *(const f4*)&wsrc[(tid + r * 256) * 4];

        __syncthreads();                 // prior compute (or epilogue prep) done
        #pragma unroll
        for (int j = 0; j < 4; ++j) {
            As[f4i * 4 + j][mrow]      = av0[j];
            As[f4i * 4 + j][mrow + 32] = av1[j];
        }
        #pragma unroll
        for (int r = 0; r < 4; ++r)      // Bs half 0: W rows wrow + 4r (0..15)
            *(f4*)&Bs[(wrow + 4 * r) * 256 + wcol] = bv[r];
        __syncthreads();
        #pragma unroll
        for (int k = 0; k < 16; ++k) {
            f4 av = *(const f4*)&As[k][ty * 4];
            f4 bq[4];
            #pragma unroll
            for (int gq = 0; gq < 4; ++gq) bq[gq] = *(const f4*)&Bs[k * 256 + gq * 64 + tx * 4];
            #pragma unroll
            for (int rr = 0; rr < 4; ++rr)
                #pragma unroll
                for (int gq = 0; gq < 4; ++gq)
                    acc[rr][gq] += av[rr] * bq[gq];
        }
        __syncthreads();
        #pragma unroll
        for (int r = 0; r < 4; ++r)      // Bs half 1: W rows 16 + wrow + 4r
            *(f4*)&Bs[(wrow + 4 * r) * 256 + wcol] = bv[4 + r];
        __syncthreads();
        #pragma unroll
        for (int k = 0; k < 16; ++k) {
            f4 av = *(const f4*)&As[16 + k][ty * 4];
            f4 bq[4];
            #pragma unroll
            for (int gq = 0; gq < 4; ++gq) bq[gq] = *(const f4*)&Bs[k * 256 + gq * 64 + tx * 4];
            #pragma unroll
            for (int rr = 0; rr < 4; ++rr)
                #pragma unroll
                for (int gq = 0; gq < 4; ++gq)
                    acc[rr][gq] += av[rr] * bq[gq];
        }
    }

    f4 bb[4];
    #pragma unroll
    for (int gq = 0; gq < 4; ++gq) {
        f4 v1 = *(const f4*)&b1[gq * 64 + tx * 4];
        f4 v2 = *(const f4*)&b2[gq * 64 + tx * 4];
        bb[gq] = v1 + v2;
    }

    f4 hreg[4];
    #pragma unroll
    for (int rr = 0; rr < 4; ++rr) {
        const int i = i0 + ty * 4 + rr;
        const bool valid = (i < 1000);
        f4 gv[4];
        #pragma unroll
        for (int gq = 0; gq < 4; ++gq) gv[gq] = acc[rr][gq] + bb[gq];
        if (WxE && valid) {
            float x0 = AX[(size_t)i * 6144 + t * 128 + b * 2 + 0];
            float x1 = AX[(size_t)i * 6144 + t * 128 + b * 2 + 1];
            #pragma unroll
            for (int gq = 0; gq < 4; ++gq)
                #pragma unroll
                for (int hh = 0; hh < 4; ++hh) {
                    int gc = gq * 64 + tx * 4 + hh;
                    gv[gq][hh] = fmaf(x0, wx[gc * 2 + 0],
                                 fmaf(x1, wx[gc * 2 + 1], gv[gq][hh]));
                }
        }
        f4 hnew = {0.f, 0.f, 0.f, 0.f};
        if (valid) {
            const size_t base = ((size_t)b * 1000 + i) * 64 + tx * 4;
            f4 cold = *(const f4*)&Cst[base];
            f4 cnew;
            #pragma unroll
            for (int hh = 0; hh < 4; ++hh) {
                float ig = 1.f / (1.f + expf(-gv[0][hh]));
                float fg = 1.f / (1.f + expf(-gv[1][hh]));
                float og = 1.f / (1.f + expf(-gv[2][hh]));
                float gg = tanhf(gv[3][hh]);
                float c  = fg * cold[hh] + ig * gg;
                cnew[hh] = c;
                hnew[hh] = og * tanhf(c);
            }
            *(f4*)&Cst[base] = cnew;
        }
        hreg[rr] = hnew;
    }

    __syncthreads();                     // all As/Bs reads done before overlay
    #pragma unroll
    for (int hh = 0; hh < 4; ++hh) {
        h4 vh, vl;
        #pragma unroll
        for (int rr = 0; rr < 4; ++rr) {
            float v = hreg[rr][hh];
            _Float16 hi = (_Float16)v;
            vh[rr] = hi;
            vl[rr] = (_Float16)((v - (float)hi) * 2048.f);
        }
        *(h4*)&Sh[tx * 4 + hh][ty * 4] = vh;
        *(h4*)&Sl[tx * 4 + hh][ty * 4] = vl;
    }
    __syncthreads();
    #pragma unroll
    for (int pass = 0; pass < 2; ++pass) {
        const int c = pass * 256 + tid;
        const int row = c >> 3;
        const int off = (c & 7) * 8;
        const size_t go = (size_t)(nbase + b * 64 + row) * 1024 + i0 + off;
        *(h8*)&HTh[go] = *(const h8*)&Sh[row][off];
        *(h8*)&HTl[go] = *(const h8*)&Sl[row][off];
    }
}

// ---------------- prologue gates (R12-proven, unchanged; runs once) ----------------
__global__ __launch_bounds__(256) void gates_f(
    const float* __restrict__ AHC, int two,
    const float* __restrict__ WT,
    const float* __restrict__ b1, const float* __restrict__ b2,
    const float* __restrict__ AX, const float* __restrict__ WxE, int t,
    float* __restrict__ Cst,
    _Float16* __restrict__ HTh, _Float16* __restrict__ HTl, int nbase)
{
    __shared__ __align__(16) char smem[43520];
    float (*As)[68] = (float(*)[68])smem;
    float *Bs       = (float*)(smem + 8704);
    float *wx       = (float*)(smem + 41472);
    _Float16 (*Sh)[80] = (_Float16(*)[80])smem;
    _Float16 (*Sl)[80] = (_Float16(*)[80])(smem + 10240);
    const int tid = threadIdx.x;
    const int tx = tid & 15;
    const int ty = tid >> 4;
    const int i0 = (blockIdx.x >> 6) * 64;
    const int b  = blockIdx.x & 63;
    const int mrow = tid >> 3;
    const int f4i  = tid & 7;

    if (WxE && tid < 128) ((f4*)wx)[tid] = ((const f4*)WxE)[tid];

    f4 acc[4][4];
    #pragma unroll
    for (int r = 0; r < 4; ++r)
        #pragma unroll
        for (int gq = 0; gq < 4; ++gq) acc[r][gq] = (f4){0.f, 0.f, 0.f, 0.f};

    const int nchunk = two ? 4 : 2;
    for (int ch = 0; ch < nchunk; ++ch) {
        const int coff = ((ch < 2) ? 0 : 4096) + b * 64;
        const int koff = (ch & 1) * 32;
        f4 av0 = *(const f4*)&AHC[(size_t)(i0 + mrow) * 8192 + coff + koff + f4i * 4];
        f4 av1 = *(const f4*)&AHC[(size_t)(i0 + mrow + 32) * 8192 + coff + koff + f4i * 4];
        const float* wsrc = WT + ch * 8192;
        f4 bv[8];
        #pragma unroll
        for (int r = 0; r < 8; ++r) bv[r] = *(const f4*)&wsrc[(tid + r * 256) * 4];
        __syncthreads();
        #pragma unroll
        for (int j = 0; j < 4; ++j) {
            As[f4i * 4 + j][mrow]      = av0[j];
            As[f4i * 4 + j][mrow + 32] = av1[j];
        }
        #pragma unroll
        for (int r = 0; r < 8; ++r) *(f4*)&Bs[(tid + r * 256) * 4] = bv[r];
        __syncthreads();
        #pragma unroll
        for (int k = 0; k < 32; ++k) {
            f4 av = *(const f4*)&As[k][ty * 4];
            f4 bq[4];
            #pragma unroll
            for (int gq = 0; gq < 4; ++gq) bq[gq] = *(const f4*)&Bs[k * 256 + gq * 64 + tx * 4];
            #pragma unroll
            for (int rr = 0; rr < 4; ++rr)
                #pragma unroll
                for (int gq = 0; gq < 4; ++gq)
                    acc[rr][gq] += av[rr] * bq[gq];
        }
    }

    f4 bb[4];
    #pragma unroll
    for (int gq = 0; gq < 4; ++gq) {
        f4 v1 = *(const f4*)&b1[gq * 64 + tx * 4];
        f4 v2 = *(const f4*)&b2[gq * 64 + tx * 4];
        bb[gq] = v1 + v2;
    }

    f4 hreg[4];
    #pragma unroll
    for (int rr = 0; rr < 4; ++rr) {
        const int i = i0 + ty * 4 + rr;
        const bool valid = (i < 1000);
        f4 gv[4];
        #pragma unroll
        for (int gq = 0; gq < 4; ++gq) gv[gq] = acc[rr][gq] + bb[gq];
        if (WxE && valid) {
            float x0 = AX[(size_t)i * 6144 + t * 128 + b * 2 + 0];
            float x1 = AX[(size_t)i * 6144 + t * 128 + b * 2 + 1];
            #pragma unroll
            for (int gq = 0; gq < 4; ++gq)
                #pragma unroll
                for (int hh = 0; hh < 4; ++hh) {
                    int gc = gq * 64 + tx * 4 + hh;
                    gv[gq][hh] = fmaf(x0, wx[gc * 2 + 0],
                                 fmaf(x1, wx[gc * 2 + 1], gv[gq][hh]));
                }
        }
        f4 hnew = {0.f, 0.f, 0.f, 0.f};
        if (valid) {
            const size_t base = ((size_t)b * 1000 + i) * 64 + tx * 4;
            f4 cold = *(const f4*)&Cst[base];
            f4 cnew;
            #pragma unroll
            for (int hh = 0; hh < 4; ++hh) {
                float ig = 1.f / (1.f + expf(-gv[0][hh]));
                float fg = 1.f / (1.f + expf(-gv[1][hh]));
                float og = 1.f / (1.f + expf(-gv[2][hh]));
                float gg = tanhf(gv[3][hh]);
                float c  = fg * cold[hh] + ig * gg;
                cnew[hh] = c;
                hnew[hh] = og * tanhf(c);
            }
            *(f4*)&Cst[base] = cnew;
        }
        hreg[rr] = hnew;
    }

    __syncthreads();
    #pragma unroll
    for (int hh = 0; hh < 4; ++hh) {
        h4 vh, vl;
        #pragma unroll
        for (int rr = 0; rr < 4; ++rr) {
            float v = hreg[rr][hh];
            _Float16 hi = (_Float16)v;
            vh[rr] = hi;
            vl[rr] = (_Float16)((v - (float)hi) * 2048.f);
        }
        *(h4*)&Sh[tx * 4 + hh][ty * 4] = vh;
        *(h4*)&Sl[tx * 4 + hh][ty * 4] = vl;
    }
    __syncthreads();
    #pragma unroll
    for (int pass = 0; pass < 2; ++pass) {
        const int c = pass * 256 + tid;
        const int row = c >> 3;
        const int off = (c & 7) * 8;
        const size_t go = (size_t)(nbase + b * 64 + row) * 1024 + i0 + off;
        *(h8*)&HTh[go] = *(const h8*)&Sh[row][off];
        *(h8*)&HTl[go] = *(const h8*)&Sl[row][off];
    }
}

// ---------------- final projection from HT rows 4096: (H1^T split f16) ----------------
__global__ __launch_bounds__(256) void proj_f16(const _Float16* __restrict__ HTh,
                                                const _Float16* __restrict__ HTl,
                                                const float* __restrict__ Wpj,
                                                const float* __restrict__ bp,
                                                float* __restrict__ out)
{
    int i = blockIdx.x * 256 + threadIdx.x;
    if (i >= 1000) return;
    int b = blockIdx.y;
    float hv[64];
    #pragma unroll
    for (int h = 0; h < 64; ++h) {
        size_t o = (size_t)(4096 + b * 64 + h) * 1024 + i;
        hv[h] = (float)HTh[o] + (float)HTl[o] * (1.f / 2048.f);
    }
    #pragma unroll
    for (int hor = 0; hor < 12; ++hor) {
        float s = bp[hor];
        #pragma unroll
        for (int h = 0; h < 64; ++h) s = fmaf(hv[h], Wpj[hor * 64 + h], s);
        out[(size_t)(b * 12 + hor) * 1000 + i] = s;
    }
}

extern "C" void kernel_launch(void* const* d_in, const int* in_sizes, int n_in,
                              void* d_out, int out_size, void* d_ws, size_t ws_size,
                              hipStream_t stream)
{
    const float* x   = (const float*)d_in[0];
    const float* E1  = (const float*)d_in[1];
    const float* E2  = (const float*)d_in[2];
    const float* Wx0 = (const float*)d_in[3];
    const float* bx0 = (const float*)d_in[4];
    const float* Wh0 = (const float*)d_in[5];
    const float* bh0 = (const float*)d_in[6];
    const float* Wx1 = (const float*)d_in[7];
    const float* bx1 = (const float*)d_in[8];
    const float* Wh1 = (const float*)d_in[9];
    const float* bh1 = (const float*)d_in[10];
    const float* Wp  = (const float*)d_in[11];
    const float* bp  = (const float*)d_in[12];
    float* out = (float*)d_out;
    float* ws  = (float*)d_ws;

    float*    AX  = ws + WS_AX;
    float*    AHC = ws + WS_AHC;
    float*    C0  = ws + WS_C0;
    float*    C1  = ws + WS_C1;
    _Float16* HTh = (_Float16*)(ws + WS_HTH);
    _Float16* HTl = (_Float16*)(ws + WS_HTL);
    _Float16* Ah  = (_Float16*)(ws + WS_A16H);
    _Float16* Al  = (_Float16*)(ws + WS_A16L);
    float*    W0T = ws + WS_W0T;
    float*    W1T = ws + WS_W1T;
    float*    At  = ws + WS_C0;              // alias: dead before the big zero
    _Float16* XTh = (_Float16*)(ws + WS_C1); // alias: dead before zero
    _Float16* XTl = (_Float16*)(ws + WS_HTH);// alias: dead before zero

    compute_A<<<1000, 256, 0, stream>>>(E1, E2, At);
    transpose_xs<<<3072, 256, 0, stream>>>(x, XTh, XTl);
    prep_A<<<4096, 256, 0, stream>>>(At, Ah, Al);
    gemm_ax<<<768, 256, 0, stream>>>(Ah, Al, XTh, XTl, AX);
    prep_w<<<192, 256, 0, stream>>>(Wh0, Wx1, Wh1, W0T, W1T);
    zero_kernel<<<24384, 256, 0, stream>>>(AHC, 6242304);

    gates_f<<<1024, 256, 0, stream>>>(AHC, 0, W0T, bh0, bx0,
                                      AX, Wx0, 0, C0, HTh, HTl, 0);
    for (int t = 0; t < 48; ++t) {
        gemm_m<<<1024, 256, 0, stream>>>(Ah, Al, HTh, HTl, AHC);
        gates_c<<<2048, 256, 0, stream>>>(AHC, W1T, W0T, bh1, bx1, bh0, bx0,
                                          AX, Wx0, (t + 1) & 47, C1, C0, HTh, HTl);
    }
    proj_f16<<<dim3(4, 64), 256, 0, stream>>>(HTh, HTl, Wp, bp, out);
    (void)in_sizes; (void)n_in; (void)out_size; (void)ws_size;
}

// Round 16
// 6921.597 us; speedup vs baseline: 4.6775x; 1.1099x over previous
//
#include <hip/hip_runtime.h>
#include <math.h>

typedef float f4 __attribute__((ext_vector_type(4)));
typedef _Float16 h4 __attribute__((ext_vector_type(4)));
typedef _Float16 h8 __attribute__((ext_vector_type(8)));

// fast LSTM activations: v_exp_f32 + v_rcp_f32 (saturate correctly at +/-inf)
__device__ __forceinline__ float fsig(float x) {
    return __builtin_amdgcn_rcpf(1.f + __expf(-x));
}
__device__ __forceinline__ float ftanh(float x) {
    return fmaf(-2.f, __builtin_amdgcn_rcpf(1.f + __expf(2.f * x)), 1.f);
}

// ---------------- workspace layout (float offsets), total 32,210,944 = 128.84 MB (R10-proven) ----
#define WS_AX    0
#define WS_AHC   6144000
#define WS_C0    14532608
#define WS_C1    18628608
#define WS_HTH   22724608
#define WS_HTL   26918912
#define WS_A16H  31113216
#define WS_A16L  31637504
#define WS_W0T   32161792
#define WS_W1T   32178176
// end = 32,210,944

// ---------------- A = softmax(relu(E1 @ E2^T)) in fp64, store A^T ----------------
__global__ __launch_bounds__(256) void compute_A(const float* __restrict__ E1,
                                                 const float* __restrict__ E2,
                                                 float* __restrict__ At)
{
    __shared__ double z[1000];
    __shared__ double red[256];
    __shared__ double e1[16];
    const int i = blockIdx.x;
    const int tid = threadIdx.x;
    if (tid < 16) e1[tid] = (double)E1[i * 16 + tid];
    __syncthreads();
    double lmax = -1e300;
    for (int j = tid; j < 1000; j += 256) {
        double s = 0.0;
        #pragma unroll
        for (int c = 0; c < 16; ++c) s += e1[c] * (double)E2[j * 16 + c];
        if (s < 0.0) s = 0.0;
        z[j] = s;
        if (s > lmax) lmax = s;
    }
    red[tid] = lmax; __syncthreads();
    for (int off = 128; off > 0; off >>= 1) {
        if (tid < off) red[tid] = fmax(red[tid], red[tid + off]);
        __syncthreads();
    }
    const double zmax = red[0];
    __syncthreads();
    double lsum = 0.0;
    for (int j = tid; j < 1000; j += 256) {
        double e = exp(z[j] - zmax);
        z[j] = e;
        lsum += e;
    }
    red[tid] = lsum; __syncthreads();
    for (int off = 128; off > 0; off >>= 1) {
        if (tid < off) red[tid] += red[tid + off];
        __syncthreads();
    }
    const double inv = 1.0 / red[0];
    for (int j = tid; j < 1000; j += 256)
        At[(size_t)j * 1000 + i] = (float)(z[j] * inv);
}

// ---------------- x [B,T,N,C] -> XrT split f16 [n=t*128+b*2+c][j] ----------------
__global__ __launch_bounds__(256) void transpose_xs(const float* __restrict__ x,
                                                    _Float16* __restrict__ XTh,
                                                    _Float16* __restrict__ XTl)
{
    const int bid = blockIdx.x;
    const int t = bid >> 6, b = bid & 63;
    const int tid = threadIdx.x;
    const size_t xbase = ((size_t)(b * 48 + t)) * 2000;
    const size_t r0 = (size_t)(t * 128 + b * 2) * 1024;
    for (int j = tid; j < 1024; j += 256) {
        float v0 = 0.f, v1 = 0.f;
        if (j < 1000) {
            float2 v = *(const float2*)&x[xbase + (size_t)j * 2];
            v0 = v.x; v1 = v.y;
        }
        _Float16 p0 = (_Float16)v0, p1 = (_Float16)v1;
        XTh[r0 + j]        = p0;
        XTl[r0 + j]        = (_Float16)((v0 - (float)p0) * 2048.f);
        XTh[r0 + 1024 + j] = p1;
        XTl[r0 + 1024 + j] = (_Float16)((v1 - (float)p1) * 2048.f);
    }
}

__global__ __launch_bounds__(256) void zero_kernel(float* __restrict__ p, int n4)
{
    int i = blockIdx.x * 256 + threadIdx.x;
    if (i < n4) { f4 z = {0.f, 0.f, 0.f, 0.f}; ((f4*)p)[i] = z; }
}

// ---------------- weight transposes to [k][256] fp32 (once; R7-proven) ----------------
__global__ __launch_bounds__(256) void prep_w(const float* __restrict__ Wh0,
                                              const float* __restrict__ Wx1,
                                              const float* __restrict__ Wh1,
                                              float* __restrict__ W0T,
                                              float* __restrict__ W1T)
{
    int idx = blockIdx.x * 256 + threadIdx.x;
    if (idx < 16384) {
        int k = idx >> 8, o = idx & 255;
        W0T[idx] = Wh0[o * 64 + k];
    }
    int j = idx - 16384;
    if (j >= 0 && j < 32768) {
        int k = j >> 8, o = j & 255;
        W1T[j] = (k < 64) ? Wx1[o * 64 + k] : Wh1[o * 64 + (k - 64)];
    }
}

// ---------------- split A^T fp32 -> Ah/Al f16 [m=1024][k=1024] ----------------
__global__ __launch_bounds__(256) void prep_A(const float* __restrict__ At,
                                              _Float16* __restrict__ Ahh,
                                              _Float16* __restrict__ All)
{
    int idx = blockIdx.x * 256 + threadIdx.x;   // 1,048,576
    int m = idx >> 10, k = idx & 1023;
    float v = (m < 1000 && k < 1000) ? At[(size_t)k * 1000 + m] : 0.f;
    _Float16 hi = (_Float16)v;
    Ahh[idx] = hi;
    All[idx] = (_Float16)((v - (float)hi) * 2048.f);
}

// ---------------- shared MFMA GEMM machinery (R12-proven body) ----------------
#define GL16(srcp, dstoff) \
    __builtin_amdgcn_global_load_lds((const __attribute__((address_space(1))) unsigned int*)(srcp), \
        (__attribute__((address_space(3))) unsigned int*)(lds + (dstoff)), 16, 0, 0)

__device__ __forceinline__ int swzb(int row, int lg) {
    return row * 64 + ((lg ^ ((row ^ (row >> 2)) & 3)) << 4);
}

// AHC[1024][8192] = A @ HT^T ; XCD-aware n mapping.
__global__ __launch_bounds__(256, 2) void gemm_m(
    const _Float16* __restrict__ Ahg, const _Float16* __restrict__ Alg,
    const _Float16* __restrict__ Bhg, const _Float16* __restrict__ Blg,
    float* __restrict__ Cout)
{
    __shared__ __align__(1024) char lds[24576];
    const int tid = threadIdx.x;
    const int lane = tid & 63;
    const int w = tid >> 6;
    const int lg = lane >> 4, l15 = lane & 15;
    const int xcd = blockIdx.x & 7;
    const int j = blockIdx.x >> 3;
    const int m0 = (j >> 3) * 64;
    const int n0 = (xcd * 8 + (j & 7)) * 128;

    const int r16 = lane >> 2;
    const int sd = lane & 3;
    const char* src[6];
    #pragma unroll
    for (int q = 0; q < 6; ++q) {
        const int c = w * 6 + q;
        int row;
        const _Float16* g;
        if (c < 4)       { row = (c)      * 16 + r16; g = Ahg + (size_t)(m0 + row) * 1024; }
        else if (c < 8)  { row = (c - 4)  * 16 + r16; g = Alg + (size_t)(m0 + row) * 1024; }
        else if (c < 16) { row = (c - 8)  * 16 + r16; g = Bhg + (size_t)(n0 + row) * 1024; }
        else             { row = (c - 16) * 16 + r16; g = Blg + (size_t)(n0 + row) * 1024; }
        const int cg = sd ^ ((row ^ (row >> 2)) & 3);
        src[q] = (const char*)(g + cg * 8);
    }

    f4 acc0[4][2], acc1[4][2];
    #pragma unroll
    for (int a = 0; a < 4; ++a)
        #pragma unroll
        for (int b = 0; b < 2; ++b) {
            acc0[a][b] = (f4){0.f, 0.f, 0.f, 0.f};
            acc1[a][b] = (f4){0.f, 0.f, 0.f, 0.f};
        }

    for (int ks = 0; ks < 32; ++ks) {
        const int kadv = ks * 64;
        #pragma unroll
        for (int q = 0; q < 6; ++q)
            GL16(src[q] + kadv, (w * 6 + q) * 1024);
        __syncthreads();

        h8 fa[4], fl[4], bh[2], bl[2];
        #pragma unroll
        for (int mf = 0; mf < 4; ++mf) {
            const int ob = swzb(mf * 16 + l15, lg);
            fa[mf] = *(const h8*)(lds + ob);
            fl[mf] = *(const h8*)(lds + 4096 + ob);
        }
        #pragma unroll
        for (int nf = 0; nf < 2; ++nf) {
            const int ob = swzb(w * 32 + nf * 16 + l15, lg);
            bh[nf] = *(const h8*)(lds + 8192 + ob);
            bl[nf] = *(const h8*)(lds + 16384 + ob);
        }
        __syncthreads();

        #pragma unroll
        for (int nf = 0; nf < 2; ++nf)
            #pragma unroll
            for (int mf = 0; mf < 4; ++mf) {
                acc0[mf][nf] = __builtin_amdgcn_mfma_f32_16x16x32_f16(fa[mf], bh[nf], acc0[mf][nf], 0, 0, 0);
                acc1[mf][nf] = __builtin_amdgcn_mfma_f32_16x16x32_f16(fa[mf], bl[nf], acc1[mf][nf], 0, 0, 0);
                acc1[mf][nf] = __builtin_amdgcn_mfma_f32_16x16x32_f16(fl[mf], bh[nf], acc1[mf][nf], 0, 0, 0);
            }
    }

    #pragma unroll
    for (int mf = 0; mf < 4; ++mf)
        #pragma unroll
        for (int nf = 0; nf < 2; ++nf) {
            const int row = m0 + mf * 16 + lg * 4;
            const int col = n0 + w * 32 + nf * 16 + l15;
            #pragma unroll
            for (int e = 0; e < 4; ++e)
                Cout[(size_t)(row + e) * 8192 + col] =
                    acc0[mf][nf][e] + acc1[mf][nf][e] * (1.f / 2048.f);
        }
}

// AX[1024][6144] = A @ XrT^T (same body; stride 6144; grid 768).
__global__ __launch_bounds__(256, 2) void gemm_ax(
    const _Float16* __restrict__ Ahg, const _Float16* __restrict__ Alg,
    const _Float16* __restrict__ Bhg, const _Float16* __restrict__ Blg,
    float* __restrict__ Cout)
{
    __shared__ __align__(1024) char lds[24576];
    const int tid = threadIdx.x;
    const int lane = tid & 63;
    const int w = tid >> 6;
    const int lg = lane >> 4, l15 = lane & 15;
    const int m0 = (blockIdx.x & 15) * 64;
    const int n0 = (blockIdx.x >> 4) * 128;

    const int r16 = lane >> 2;
    const int sd = lane & 3;
    const char* src[6];
    #pragma unroll
    for (int q = 0; q < 6; ++q) {
        const int c = w * 6 + q;
        int row;
        const _Float16* g;
        if (c < 4)       { row = (c)      * 16 + r16; g = Ahg + (size_t)(m0 + row) * 1024; }
        else if (c < 8)  { row = (c - 4)  * 16 + r16; g = Alg + (size_t)(m0 + row) * 1024; }
        else if (c < 16) { row = (c - 8)  * 16 + r16; g = Bhg + (size_t)(n0 + row) * 1024; }
        else             { row = (c - 16) * 16 + r16; g = Blg + (size_t)(n0 + row) * 1024; }
        const int cg = sd ^ ((row ^ (row >> 2)) & 3);
        src[q] = (const char*)(g + cg * 8);
    }

    f4 acc0[4][2], acc1[4][2];
    #pragma unroll
    for (int a = 0; a < 4; ++a)
        #pragma unroll
        for (int b = 0; b < 2; ++b) {
            acc0[a][b] = (f4){0.f, 0.f, 0.f, 0.f};
            acc1[a][b] = (f4){0.f, 0.f, 0.f, 0.f};
        }

    for (int ks = 0; ks < 32; ++ks) {
        const int kadv = ks * 64;
        #pragma unroll
        for (int q = 0; q < 6; ++q)
            GL16(src[q] + kadv, (w * 6 + q) * 1024);
        __syncthreads();

        h8 fa[4], fl[4], bh[2], bl[2];
        #pragma unroll
        for (int mf = 0; mf < 4; ++mf) {
            const int ob = swzb(mf * 16 + l15, lg);
            fa[mf] = *(const h8*)(lds + ob);
            fl[mf] = *(const h8*)(lds + 4096 + ob);
        }
        #pragma unroll
        for (int nf = 0; nf < 2; ++nf) {
            const int ob = swzb(w * 32 + nf * 16 + l15, lg);
            bh[nf] = *(const h8*)(lds + 8192 + ob);
            bl[nf] = *(const h8*)(lds + 16384 + ob);
        }
        __syncthreads();

        #pragma unroll
        for (int nf = 0; nf < 2; ++nf)
            #pragma unroll
            for (int mf = 0; mf < 4; ++mf) {
                acc0[mf][nf] = __builtin_amdgcn_mfma_f32_16x16x32_f16(fa[mf], bh[nf], acc0[mf][nf], 0, 0, 0);
                acc1[mf][nf] = __builtin_amdgcn_mfma_f32_16x16x32_f16(fa[mf], bl[nf], acc1[mf][nf], 0, 0, 0);
                acc1[mf][nf] = __builtin_amdgcn_mfma_f32_16x16x32_f16(fl[mf], bh[nf], acc1[mf][nf], 0, 0, 0);
            }
    }

    #pragma unroll
    for (int mf = 0; mf < 4; ++mf)
        #pragma unroll
        for (int nf = 0; nf < 2; ++nf) {
            const int row = m0 + mf * 16 + lg * 4;
            const int col = n0 + w * 32 + nf * 16 + l15;
            #pragma unroll
            for (int e = 0; e < 4; ++e)
                Cout[(size_t)(row + e) * 6144 + col] =
                    acc0[mf][nf][e] + acc1[mf][nf][e] * (1.f / 2048.f);
        }
}

// ---------------- combined gates (R15-proven structure, fast activations) ----------------
__global__ __launch_bounds__(256) void gates_c(
    const float* __restrict__ AHC,
    const float* __restrict__ W1T, const float* __restrict__ W0T,
    const float* __restrict__ bh1, const float* __restrict__ bx1,
    const float* __restrict__ bh0, const float* __restrict__ bx0,
    const float* __restrict__ AX, const float* __restrict__ Wx0E, int tnext,
    float* __restrict__ C1, float* __restrict__ C0,
    _Float16* __restrict__ HTh, _Float16* __restrict__ HTl)
{
    __shared__ __align__(16) char smem[27136];
    float (*As)[68] = (float(*)[68])smem;                 // 8,704 B
    float *Bs       = (float*)(smem + 8704);              // 16,384 B (16 k-rows)
    float *wx       = (float*)(smem + 25088);             // 2,048 B
    _Float16 (*Sh)[80] = (_Float16(*)[80])smem;           // overlay
    _Float16 (*Sl)[80] = (_Float16(*)[80])(smem + 10240); // overlay, ends 20,480

    const int half = blockIdx.x >> 10;
    const int bidx = blockIdx.x & 1023;
    const int two  = half ^ 1;
    const float* WT  = half ? W0T : W1T;
    const float* b1  = half ? bh0 : bh1;
    const float* b2  = half ? bx0 : bx1;
    const float* WxE = half ? Wx0E : nullptr;
    float* Cst = half ? C0 : C1;
    const int nbase = half ? 0 : 4096;
    const int t = tnext;

    const int tid = threadIdx.x;
    const int tx = tid & 15;
    const int ty = tid >> 4;
    const int i0 = (bidx >> 6) * 64;
    const int b  = bidx & 63;
    const int mrow = tid >> 3;          // 0..31
    const int f4i  = tid & 7;
    const int wrow = tid >> 6;          // 0..3
    const int wcol = (tid & 63) * 4;

    if (WxE && tid < 128) ((f4*)wx)[tid] = ((const f4*)WxE)[tid];

    f4 acc[4][4];
    #pragma unroll
    for (int r = 0; r < 4; ++r)
        #pragma unroll
        for (int gq = 0; gq < 4; ++gq) acc[r][gq] = (f4){0.f, 0.f, 0.f, 0.f};

    const int nchunk = two ? 4 : 2;
    for (int ch = 0; ch < nchunk; ++ch) {
        const int coff = ((ch < 2) ? 0 : 4096) + b * 64;
        const int koff = (ch & 1) * 32;
        f4 av0 = *(const f4*)&AHC[(size_t)(i0 + mrow) * 8192 + coff + koff + f4i * 4];
        f4 av1 = *(const f4*)&AHC[(size_t)(i0 + mrow + 32) * 8192 + coff + koff + f4i * 4];
        const float* wsrc = WT + ch * 8192;
        f4 bv[8];
        #pragma unroll
        for (int r = 0; r < 8; ++r) bv[r] = *(const f4*)&wsrc[(tid + r * 256) * 4];

        __syncthreads();
        #pragma unroll
        for (int j = 0; j < 4; ++j) {
            As[f4i * 4 + j][mrow]      = av0[j];
            As[f4i * 4 + j][mrow + 32] = av1[j];
        }
        #pragma unroll
        for (int r = 0; r < 4; ++r)
            *(f4*)&Bs[(wrow + 4 * r) * 256 + wcol] = bv[r];
        __syncthreads();
        #pragma unroll
        for (int k = 0; k < 16; ++k) {
            f4 av = *(const f4*)&As[k][ty * 4];
            f4 bq[4];
            #pragma unroll
            for (int gq = 0; gq < 4; ++gq) bq[gq] = *(const f4*)&Bs[k * 256 + gq * 64 + tx * 4];
            #pragma unroll
            for (int rr = 0; rr < 4; ++rr)
                #pragma unroll
                for (int gq = 0; gq < 4; ++gq)
                    acc[rr][gq] += av[rr] * bq[gq];
        }
        __syncthreads();
        #pragma unroll
        for (int r = 0; r < 4; ++r)
            *(f4*)&Bs[(wrow + 4 * r) * 256 + wcol] = bv[4 + r];
        __syncthreads();
        #pragma unroll
        for (int k = 0; k < 16; ++k) {
            f4 av = *(const f4*)&As[16 + k][ty * 4];
            f4 bq[4];
            #pragma unroll
            for (int gq = 0; gq < 4; ++gq) bq[gq] = *(const f4*)&Bs[k * 256 + gq * 64 + tx * 4];
            #pragma unroll
            for (int rr = 0; rr < 4; ++rr)
                #pragma unroll
                for (int gq = 0; gq < 4; ++gq)
                    acc[rr][gq] += av[rr] * bq[gq];
        }
    }

    f4 bb[4];
    #pragma unroll
    for (int gq = 0; gq < 4; ++gq) {
        f4 v1 = *(const f4*)&b1[gq * 64 + tx * 4];
        f4 v2 = *(const f4*)&b2[gq * 64 + tx * 4];
        bb[gq] = v1 + v2;
    }

    f4 hreg[4];
    #pragma unroll
    for (int rr = 0; rr < 4; ++rr) {
        const int i = i0 + ty * 4 + rr;
        const bool valid = (i < 1000);
        f4 gv[4];
        #pragma unroll
        for (int gq = 0; gq < 4; ++gq) gv[gq] = acc[rr][gq] + bb[gq];
        if (WxE && valid) {
            float x0 = AX[(size_t)i * 6144 + t * 128 + b * 2 + 0];
            float x1 = AX[(size_t)i * 6144 + t * 128 + b * 2 + 1];
            #pragma unroll
            for (int gq = 0; gq < 4; ++gq)
                #pragma unroll
                for (int hh = 0; hh < 4; ++hh) {
                    int gc = gq * 64 + tx * 4 + hh;
                    gv[gq][hh] = fmaf(x0, wx[gc * 2 + 0],
                                 fmaf(x1, wx[gc * 2 + 1], gv[gq][hh]));
                }
        }
        f4 hnew = {0.f, 0.f, 0.f, 0.f};
        if (valid) {
            const size_t base = ((size_t)b * 1000 + i) * 64 + tx * 4;
            f4 cold = *(const f4*)&Cst[base];
            f4 cnew;
            #pragma unroll
            for (int hh = 0; hh < 4; ++hh) {
                float ig = fsig(gv[0][hh]);
                float fg = fsig(gv[1][hh]);
                float og = fsig(gv[2][hh]);
                float gg = ftanh(gv[3][hh]);
                float c  = fg * cold[hh] + ig * gg;
                cnew[hh] = c;
                hnew[hh] = og * ftanh(c);
            }
            *(f4*)&Cst[base] = cnew;
        }
        hreg[rr] = hnew;
    }

    __syncthreads();
    #pragma unroll
    for (int hh = 0; hh < 4; ++hh) {
        h4 vh, vl;
        #pragma unroll
        for (int rr = 0; rr < 4; ++rr) {
            float v = hreg[rr][hh];
            _Float16 hi = (_Float16)v;
            vh[rr] = hi;
            vl[rr] = (_Float16)((v - (float)hi) * 2048.f);
        }
        *(h4*)&Sh[tx * 4 + hh][ty * 4] = vh;
        *(h4*)&Sl[tx * 4 + hh][ty * 4] = vl;
    }
    __syncthreads();
    #pragma unroll
    for (int pass = 0; pass < 2; ++pass) {
        const int c = pass * 256 + tid;
        const int row = c >> 3;
        const int off = (c & 7) * 8;
        const size_t go = (size_t)(nbase + b * 64 + row) * 1024 + i0 + off;
        *(h8*)&HTh[go] = *(const h8*)&Sh[row][off];
        *(h8*)&HTl[go] = *(const h8*)&Sl[row][off];
    }
}

// ---------------- prologue gates (R12-proven; fast activations; runs once) ----------------
__global__ __launch_bounds__(256) void gates_f(
    const float* __restrict__ AHC, int two,
    const float* __restrict__ WT,
    const float* __restrict__ b1, const float* __restrict__ b2,
    const float* __restrict__ AX, const float* __restrict__ WxE, int t,
    float* __restrict__ Cst,
    _Float16* __restrict__ HTh, _Float16* __restrict__ HTl, int nbase)
{
    __shared__ __align__(16) char smem[43520];
    float (*As)[68] = (float(*)[68])smem;
    float *Bs       = (float*)(smem + 8704);
    float *wx       = (float*)(smem + 41472);
    _Float16 (*Sh)[80] = (_Float16(*)[80])smem;
    _Float16 (*Sl)[80] = (_Float16(*)[80])(smem + 10240);
    const int tid = threadIdx.x;
    const int tx = tid & 15;
    const int ty = tid >> 4;
    const int i0 = (blockIdx.x >> 6) * 64;
    const int b  = blockIdx.x & 63;
    const int mrow = tid >> 3;
    const int f4i  = tid & 7;

    if (WxE && tid < 128) ((f4*)wx)[tid] = ((const f4*)WxE)[tid];

    f4 acc[4][4];
    #pragma unroll
    for (int r = 0; r < 4; ++r)
        #pragma unroll
        for (int gq = 0; gq < 4; ++gq) acc[r][gq] = (f4){0.f, 0.f, 0.f, 0.f};

    const int nchunk = two ? 4 : 2;
    for (int ch = 0; ch < nchunk; ++ch) {
        const int coff = ((ch < 2) ? 0 : 4096) + b * 64;
        const int koff = (ch & 1) * 32;
        f4 av0 = *(const f4*)&AHC[(size_t)(i0 + mrow) * 8192 + coff + koff + f4i * 4];
        f4 av1 = *(const f4*)&AHC[(size_t)(i0 + mrow + 32) * 8192 + coff + koff + f4i * 4];
        const float* wsrc = WT + ch * 8192;
        f4 bv[8];
        #pragma unroll
        for (int r = 0; r < 8; ++r) bv[r] = *(const f4*)&wsrc[(tid + r * 256) * 4];
        __syncthreads();
        #pragma unroll
        for (int j = 0; j < 4; ++j) {
            As[f4i * 4 + j][mrow]      = av0[j];
            As[f4i * 4 + j][mrow + 32] = av1[j];
        }
        #pragma unroll
        for (int r = 0; r < 8; ++r) *(f4*)&Bs[(tid + r * 256) * 4] = bv[r];
        __syncthreads();
        #pragma unroll
        for (int k = 0; k < 32; ++k) {
            f4 av = *(const f4*)&As[k][ty * 4];
            f4 bq[4];
            #pragma unroll
            for (int gq = 0; gq < 4; ++gq) bq[gq] = *(const f4*)&Bs[k * 256 + gq * 64 + tx * 4];
            #pragma unroll
            for (int rr = 0; rr < 4; ++rr)
                #pragma unroll
                for (int gq = 0; gq < 4; ++gq)
                    acc[rr][gq] += av[rr] * bq[gq];
        }
    }

    f4 bb[4];
    #pragma unroll
    for (int gq = 0; gq < 4; ++gq) {
        f4 v1 = *(const f4*)&b1[gq * 64 + tx * 4];
        f4 v2 = *(const f4*)&b2[gq * 64 + tx * 4];
        bb[gq] = v1 + v2;
    }

    f4 hreg[4];
    #pragma unroll
    for (int rr = 0; rr < 4; ++rr) {
        const int i = i0 + ty * 4 + rr;
        const bool valid = (i < 1000);
        f4 gv[4];
        #pragma unroll
        for (int gq = 0; gq < 4; ++gq) gv[gq] = acc[rr][gq] + bb[gq];
        if (WxE && valid) {
            float x0 = AX[(size_t)i * 6144 + t * 128 + b * 2 + 0];
            float x1 = AX[(size_t)i * 6144 + t * 128 + b * 2 + 1];
            #pragma unroll
            for (int gq = 0; gq < 4; ++gq)
                #pragma unroll
                for (int hh = 0; hh < 4; ++hh) {
                    int gc = gq * 64 + tx * 4 + hh;
                    gv[gq][hh] = fmaf(x0, wx[gc * 2 + 0],
                                 fmaf(x1, wx[gc * 2 + 1], gv[gq][hh]));
                }
        }
        f4 hnew = {0.f, 0.f, 0.f, 0.f};
        if (valid) {
            const size_t base = ((size_t)b * 1000 + i) * 64 + tx * 4;
            f4 cold = *(const f4*)&Cst[base];
            f4 cnew;
            #pragma unroll
            for (int hh = 0; hh < 4; ++hh) {
                float ig = fsig(gv[0][hh]);
                float fg = fsig(gv[1][hh]);
                float og = fsig(gv[2][hh]);
                float gg = ftanh(gv[3][hh]);
                float c  = fg * cold[hh] + ig * gg;
                cnew[hh] = c;
                hnew[hh] = og * ftanh(c);
            }
            *(f4*)&Cst[base] = cnew;
        }
        hreg[rr] = hnew;
    }

    __syncthreads();
    #pragma unroll
    for (int hh = 0; hh < 4; ++hh) {
        h4 vh, vl;
        #pragma unroll
        for (int rr = 0; rr < 4; ++rr) {
            float v = hreg[rr][hh];
            _Float16 hi = (_Float16)v;
            vh[rr] = hi;
            vl[rr] = (_Float16)((v - (float)hi) * 2048.f);
        }
        *(h4*)&Sh[tx * 4 + hh][ty * 4] = vh;
        *(h4*)&Sl[tx * 4 + hh][ty * 4] = vl;
    }
    __syncthreads();
    #pragma unroll
    for (int pass = 0; pass < 2; ++pass) {
        const int c = pass * 256 + tid;
        const int row = c >> 3;
        const int off = (c & 7) * 8;
        const size_t go = (size_t)(nbase + b * 64 + row) * 1024 + i0 + off;
        *(h8*)&HTh[go] = *(const h8*)&Sh[row][off];
        *(h8*)&HTl[go] = *(const h8*)&Sl[row][off];
    }
}

// ---------------- final projection from HT rows 4096: (H1^T split f16) ----------------
__global__ __launch_bounds__(256) void proj_f16(const _Float16* __restrict__ HTh,
                                                const _Float16* __restrict__ HTl,
                                                const float* __restrict__ Wpj,
                                                const float* __restrict__ bp,
                                                float* __restrict__ out)
{
    int i = blockIdx.x * 256 + threadIdx.x;
    if (i >= 1000) return;
    int b = blockIdx.y;
    float hv[64];
    #pragma unroll
    for (int h = 0; h < 64; ++h) {
        size_t o = (size_t)(4096 + b * 64 + h) * 1024 + i;
        hv[h] = (float)HTh[o] + (float)HTl[o] * (1.f / 2048.f);
    }
    #pragma unroll
    for (int hor = 0; hor < 12; ++hor) {
        float s = bp[hor];
        #pragma unroll
        for (int h = 0; h < 64; ++h) s = fmaf(hv[h], Wpj[hor * 64 + h], s);
        out[(size_t)(b * 12 + hor) * 1000 + i] = s;
    }
}

extern "C" void kernel_launch(void* const* d_in, const int* in_sizes, int n_in,
                              void* d_out, int out_size, void* d_ws, size_t ws_size,
                              hipStream_t stream)
{
    const float* x   = (const float*)d_in[0];
    const float* E1  = (const float*)d_in[1];
    const float* E2  = (const float*)d_in[2];
    const float* Wx0 = (const float*)d_in[3];
    const float* bx0 = (const float*)d_in[4];
    const float* Wh0 = (const float*)d_in[5];
    const float* bh0 = (const float*)d_in[6];
    const float* Wx1 = (const float*)d_in[7];
    const float* bx1 = (const float*)d_in[8];
    const float* Wh1 = (const float*)d_in[9];
    const float* bh1 = (const float*)d_in[10];
    const float* Wp  = (const float*)d_in[11];
    const float* bp  = (const float*)d_in[12];
    float* out = (float*)d_out;
    float* ws  = (float*)d_ws;

    float*    AX  = ws + WS_AX;
    float*    AHC = ws + WS_AHC;
    float*    C0  = ws + WS_C0;
    float*    C1  = ws + WS_C1;
    _Float16* HTh = (_Float16*)(ws + WS_HTH);
    _Float16* HTl = (_Float16*)(ws + WS_HTL);
    _Float16* Ah  = (_Float16*)(ws + WS_A16H);
    _Float16* Al  = (_Float16*)(ws + WS_A16L);
    float*    W0T = ws + WS_W0T;
    float*    W1T = ws + WS_W1T;
    float*    At  = ws + WS_C0;              // alias: dead before the big zero
    _Float16* XTh = (_Float16*)(ws + WS_C1); // alias: dead before zero
    _Float16* XTl = (_Float16*)(ws + WS_HTH);// alias: dead before zero

    compute_A<<<1000, 256, 0, stream>>>(E1, E2, At);
    transpose_xs<<<3072, 256, 0, stream>>>(x, XTh, XTl);
    prep_A<<<4096, 256, 0, stream>>>(At, Ah, Al);
    gemm_ax<<<768, 256, 0, stream>>>(Ah, Al, XTh, XTl, AX);
    prep_w<<<192, 256, 0, stream>>>(Wh0, Wx1, Wh1, W0T, W1T);
    zero_kernel<<<24384, 256, 0, stream>>>(AHC, 6242304);

    gates_f<<<1024, 256, 0, stream>>>(AHC, 0, W0T, bh0, bx0,
                                      AX, Wx0, 0, C0, HTh, HTl, 0);
    for (int t = 0; t < 48; ++t) {
        gemm_m<<<1024, 256, 0, stream>>>(Ah, Al, HTh, HTl, AHC);
        gates_c<<<2048, 256, 0, stream>>>(AHC, W1T, W0T, bh1, bx1, bh0, bx0,
                                          AX, Wx0, (t + 1) & 47, C1, C0, HTh, HTl);
    }
    proj_f16<<<dim3(4, 64), 256, 0, stream>>>(HTh, HTl, Wp, bp, out);
    (void)in_sizes; (void)n_in; (void)out_size; (void)ws_size;
}